// Round 13
// baseline (278.536 us; speedup 1.0000x reference)
//
#include <hip/hip_runtime.h>

#define INCH 256
#define HIDF 64
#define BSH 8              // 256 nodes per bucket
#define MAXBUCK 512        // supports n up to 131072
#define CHUNK 4096         // edges per bin_records block

typedef __attribute__((ext_vector_type(8))) short short8v;  // 8 bf16 (4 VGPRs)
typedef __attribute__((ext_vector_type(4))) float f32x4;
typedef __attribute__((ext_vector_type(2))) float f32x2;

// ---------------------------------------------------------------------------
// edge dtype sniffer
// ---------------------------------------------------------------------------
__global__ void detect_i64(const unsigned int* __restrict__ ei, int* __restrict__ flag) {
    __shared__ int nonzero;
    if (threadIdx.x == 0) nonzero = 0;
    __syncthreads();
    if (ei[2 * (size_t)threadIdx.x + 1] != 0u) nonzero = 1;
    __syncthreads();
    if (threadIdx.x == 0) *flag = (nonzero == 0) ? 1 : 0;
}

__device__ __forceinline__ int edge_at(const void* ei, int is64, long long i) {
    if (is64) return (int)((const long long*)ei)[i];
    return ((const int*)ei)[i];
}

// round-to-nearest-even f32 -> bf16 (as u16 in low bits)
__device__ __forceinline__ unsigned bf16rne(float f) {
    unsigned u = __float_as_uint(f);
    return (u + 0x7fffu + ((u >> 16) & 1u)) >> 16;
}

// ---------------------------------------------------------------------------
// CSR build (count-free multisplit) — unchanged from round 12
// ---------------------------------------------------------------------------
__global__ __launch_bounds__(256) void bin_records(const void* __restrict__ ei,
                                                   const int* __restrict__ flag,
                                                   int* __restrict__ bcur,
                                                   unsigned* __restrict__ staged,
                                                   int E, int CAP) {
    __shared__ int cnt[MAXBUCK];
    __shared__ int cur[MAXBUCK];
    const int t = threadIdx.x;
    const int is64 = *flag;
    const long long base = (long long)blockIdx.x * CHUNK;

    for (int b = t; b < MAXBUCK; b += 256) cnt[b] = 0;
    __syncthreads();

    int sr[16], dr[16];
#pragma unroll
    for (int i = 0; i < 16; i++) {
        long long e = base + (long long)i * 256 + t;
        if (e < E) {
            sr[i] = edge_at(ei, is64, e);
            dr[i] = edge_at(ei, is64, (long long)E + e);
            atomicAdd(&cnt[dr[i] >> BSH], 1);
        } else {
            dr[i] = -1;
        }
    }
    __syncthreads();

    for (int b = t; b < MAXBUCK; b += 256)
        if (cnt[b]) cur[b] = b * CAP + atomicAdd(&bcur[b], cnt[b]);
    __syncthreads();

#pragma unroll
    for (int i = 0; i < 16; i++) {
        if (dr[i] >= 0) {
            int gpos = atomicAdd(&cur[dr[i] >> BSH], 1);
            staged[gpos] = (unsigned)sr[i] | ((unsigned)(dr[i] & 255) << 24);
        }
    }
}

__global__ void bucket_scan(const int* __restrict__ bcur, int* __restrict__ bbase,
                            int* __restrict__ row_start, int nbuck, int E, int n) {
    __shared__ int s[MAXBUCK];
    int t = threadIdx.x;
    int v = (t < nbuck) ? bcur[t] : 0;
    s[t] = v;
    __syncthreads();
    for (int off = 1; off < MAXBUCK; off <<= 1) {
        int add = (t >= off) ? s[t - off] : 0;
        __syncthreads();
        s[t] += add;
        __syncthreads();
    }
    if (t < nbuck) bbase[t] = s[t] - v;
    if (t == 0) {
        bbase[nbuck] = E;
        row_start[n] = E;
    }
}

__global__ __launch_bounds__(256) void bucket_finalize(const unsigned* __restrict__ staged,
                                                       const int* __restrict__ bcnts,
                                                       const int* __restrict__ bbase,
                                                       int* __restrict__ row_start,
                                                       float* __restrict__ dinv,
                                                       int* __restrict__ srcs,
                                                       int n, int CAP) {
    __shared__ int cnt[256];
    __shared__ int sc[256];
    __shared__ int cur[256];
    const int b  = blockIdx.x;
    const int t  = threadIdx.x;
    const int d0 = b << BSH;
    const int r0 = bbase[b];
    const int cb = bcnts[b];
    const size_t sb = (size_t)b * CAP;

    cnt[t] = 0;
    __syncthreads();
    for (int j = t; j < cb; j += 256) {
        unsigned rec = staged[sb + j];
        atomicAdd(&cnt[rec >> 24], 1);
    }
    __syncthreads();

    int v = cnt[t];
    sc[t] = v;
    __syncthreads();
    for (int off = 1; off < 256; off <<= 1) {
        int add = (t >= off) ? sc[t - off] : 0;
        __syncthreads();
        sc[t] += add;
        __syncthreads();
    }
    int ex = sc[t] - v;

    int node = d0 + t;
    if (node < n) {
        row_start[node] = r0 + ex;
        dinv[node] = rsqrtf((float)v + 1.0f);
    }
    cur[t] = r0 + ex;
    __syncthreads();

    for (int j = t; j < cb; j += 256) {
        unsigned rec = staged[sb + j];
        int pos = atomicAdd(&cur[rec >> 24], 1);
        srcs[pos] = (int)(rec & 0xffffffu);
    }
}

// ---------------------------------------------------------------------------
// W split+swizzle — unchanged
// ---------------------------------------------------------------------------
__global__ void wsplit(const float* __restrict__ W, unsigned short* __restrict__ whi,
                       unsigned short* __restrict__ wlo, int K) {
    int tid = blockIdx.x * 256 + threadIdx.x;
    int total = (K / 32) * 4 * 64;
    if (tid >= total) return;
    int lane = tid & 63;
    int nf   = (tid >> 6) & 3;
    int ks   = tid >> 8;
    int col  = nf * 16 + (lane & 15);
    int k0   = ks * 32 + (lane >> 4) * 8;
#pragma unroll
    for (int i = 0; i < 8; i++) {
        float w = W[(size_t)(k0 + i) * 64 + col];
        unsigned u = __float_as_uint(w);
        float hif = __uint_as_float(u & 0xffff0000u);
        whi[(size_t)tid * 8 + i] = (unsigned short)(u >> 16);
        wlo[(size_t)tid * 8 + i] = (unsigned short)(__float_as_uint(w - hif) >> 16);
    }
}

// ---------------------------------------------------------------------------
// split-bf16 MFMA GEMM — unchanged
// ---------------------------------------------------------------------------
template <int K>
__global__ __launch_bounds__(256) void gemm_mfma(const float* __restrict__ X,
                                                 const unsigned short* __restrict__ whi,
                                                 const unsigned short* __restrict__ wlo,
                                                 const float* __restrict__ dinv,
                                                 unsigned* __restrict__ Y, int n) {
    __shared__ unsigned tile[64 * 36];
    __shared__ float dl[64];
    const int t    = threadIdx.x;
    const int wid  = t >> 6;
    const int lane = t & 63;
    const int r0   = blockIdx.x * 64;

    if (t < 64) dl[t] = (r0 + t < n) ? dinv[r0 + t] : 0.f;
    __syncthreads();

    const int mrow = lane & 15;
    const int kg   = (lane >> 4) * 8;
    const int row  = r0 + wid * 16 + mrow;
    const bool rv  = row < n;

    f32x4 acc0 = {0.f, 0.f, 0.f, 0.f};
    f32x4 acc1 = {0.f, 0.f, 0.f, 0.f};
    f32x4 acc2 = {0.f, 0.f, 0.f, 0.f};
    f32x4 acc3 = {0.f, 0.f, 0.f, 0.f};

    for (int ks = 0; ks < K / 32; ks++) {
        float4 a0 = {0.f, 0.f, 0.f, 0.f}, a1 = {0.f, 0.f, 0.f, 0.f};
        if (rv) {
            const float* xp = &X[(size_t)row * K + ks * 32 + kg];
            a0 = *(const float4*)xp;
            a1 = *(const float4*)(xp + 4);
        }
        float av[8] = {a0.x, a0.y, a0.z, a0.w, a1.x, a1.y, a1.z, a1.w};
        short8v ahi, alo;
#pragma unroll
        for (int i = 0; i < 8; i++) {
            unsigned u = __float_as_uint(av[i]);
            ahi[i] = (short)(u >> 16);
            float hif = __uint_as_float(u & 0xffff0000u);
            alo[i] = (short)(__float_as_uint(av[i] - hif) >> 16);
        }
        const size_t bbase = ((size_t)ks * 4 * 64 + lane) * 8;
        short8v bh0 = *(const short8v*)&whi[bbase + 0 * 512];
        short8v bh1 = *(const short8v*)&whi[bbase + 1 * 512];
        short8v bh2 = *(const short8v*)&whi[bbase + 2 * 512];
        short8v bh3 = *(const short8v*)&whi[bbase + 3 * 512];
        short8v bl0 = *(const short8v*)&wlo[bbase + 0 * 512];
        short8v bl1 = *(const short8v*)&wlo[bbase + 1 * 512];
        short8v bl2 = *(const short8v*)&wlo[bbase + 2 * 512];
        short8v bl3 = *(const short8v*)&wlo[bbase + 3 * 512];

        acc0 = __builtin_amdgcn_mfma_f32_16x16x32_bf16(ahi, bh0, acc0, 0, 0, 0);
        acc1 = __builtin_amdgcn_mfma_f32_16x16x32_bf16(ahi, bh1, acc1, 0, 0, 0);
        acc2 = __builtin_amdgcn_mfma_f32_16x16x32_bf16(ahi, bh2, acc2, 0, 0, 0);
        acc3 = __builtin_amdgcn_mfma_f32_16x16x32_bf16(ahi, bh3, acc3, 0, 0, 0);
        acc0 = __builtin_amdgcn_mfma_f32_16x16x32_bf16(alo, bh0, acc0, 0, 0, 0);
        acc1 = __builtin_amdgcn_mfma_f32_16x16x32_bf16(alo, bh1, acc1, 0, 0, 0);
        acc2 = __builtin_amdgcn_mfma_f32_16x16x32_bf16(alo, bh2, acc2, 0, 0, 0);
        acc3 = __builtin_amdgcn_mfma_f32_16x16x32_bf16(alo, bh3, acc3, 0, 0, 0);
        acc0 = __builtin_amdgcn_mfma_f32_16x16x32_bf16(ahi, bl0, acc0, 0, 0, 0);
        acc1 = __builtin_amdgcn_mfma_f32_16x16x32_bf16(ahi, bl1, acc1, 0, 0, 0);
        acc2 = __builtin_amdgcn_mfma_f32_16x16x32_bf16(ahi, bl2, acc2, 0, 0, 0);
        acc3 = __builtin_amdgcn_mfma_f32_16x16x32_bf16(ahi, bl3, acc3, 0, 0, 0);
    }

    const int c15 = lane & 15;
#pragma unroll
    for (int nf = 0; nf < 4; nf++) {
        f32x4 a = (nf == 0) ? acc0 : (nf == 1) ? acc1 : (nf == 2) ? acc2 : acc3;
#pragma unroll
        for (int r = 0; r < 4; r++) {
            int m = (lane >> 4) * 4 + r;
            float v = a[r] * dl[wid * 16 + m];
            float pv = __shfl_xor(v, 1, 64);
            if (!(lane & 1)) {
                unsigned u = bf16rne(v) | (bf16rne(pv) << 16);
                tile[(wid * 16 + m) * 36 + nf * 8 + (c15 >> 1)] = u;
            }
        }
    }
    __syncthreads();

    {
        int lrow = t >> 2;
        int cb   = (t & 3) * 8;
        if (r0 + lrow < n) {
            uint4 w0 = *(const uint4*)&tile[lrow * 36 + cb];
            uint4 w1 = *(const uint4*)&tile[lrow * 36 + cb + 4];
            *(uint4*)&Y[(size_t)(r0 + lrow) * 32 + cb]     = w0;
            *(uint4*)&Y[(size_t)(r0 + lrow) * 32 + cb + 4] = w1;
        }
    }
}

// ---------------------------------------------------------------------------
// gather core: 4-deep row-load pipeline (mean degree 32 -> one iteration)
// lane = (edge-slot es = lane>>3, uint4-chunk fc = lane&7)
// ---------------------------------------------------------------------------
__device__ __forceinline__ void acc_pair(f32x2& a, unsigned w) {
    f32x2 v;
    v.x = __uint_as_float(w << 16);
    v.y = __uint_as_float(w & 0xffff0000u);
    a += v;   // v_pk_add_f32
}

__device__ __forceinline__ void acc_u4(f32x2* acc, uint4 u) {
    acc_pair(acc[0], u.x);
    acc_pair(acc[1], u.y);
    acc_pair(acc[2], u.z);
    acc_pair(acc[3], u.w);
}

__device__ __forceinline__ void gather_core(const unsigned* __restrict__ g32,
                                            const int* __restrict__ srcs,
                                            int s0, int s1, int node, int es, int fc,
                                            f32x2* acc) {
    // self-loop (counted once, by slot 0)
    if (es == 0) acc_u4(acc, *(const uint4*)&g32[(size_t)node * 32 + fc * 4]);

    int j = s0 + es;
    for (; j + 24 < s1; j += 32) {       // 4 rows in flight
        int a0 = srcs[j];
        int a1 = srcs[j + 8];
        int a2 = srcs[j + 16];
        int a3 = srcs[j + 24];
        uint4 u0 = *(const uint4*)&g32[(size_t)a0 * 32 + fc * 4];
        uint4 u1 = *(const uint4*)&g32[(size_t)a1 * 32 + fc * 4];
        uint4 u2 = *(const uint4*)&g32[(size_t)a2 * 32 + fc * 4];
        uint4 u3 = *(const uint4*)&g32[(size_t)a3 * 32 + fc * 4];
        acc_u4(acc, u0);
        acc_u4(acc, u1);
        acc_u4(acc, u2);
        acc_u4(acc, u3);
    }
    for (; j + 8 < s1; j += 16) {        // 2 rows in flight
        int a0 = srcs[j];
        int a1 = srcs[j + 8];
        uint4 u0 = *(const uint4*)&g32[(size_t)a0 * 32 + fc * 4];
        uint4 u1 = *(const uint4*)&g32[(size_t)a1 * 32 + fc * 4];
        acc_u4(acc, u0);
        acc_u4(acc, u1);
    }
    if (j < s1) acc_u4(acc, *(const uint4*)&g32[(size_t)srcs[j] * 32 + fc * 4]);
}

__device__ __forceinline__ void slot_reduce(f32x2* acc) {
#pragma unroll
    for (int q = 0; q < 4; q++) {
        acc[q].x += __shfl_xor(acc[q].x, 8, 64);
        acc[q].y += __shfl_xor(acc[q].y, 8, 64);
        acc[q].x += __shfl_xor(acc[q].x, 16, 64);
        acc[q].y += __shfl_xor(acc[q].y, 16, 64);
        acc[q].x += __shfl_xor(acc[q].x, 32, 64);
        acc[q].y += __shfl_xor(acc[q].y, 32, 64);
    }
}

// ---------------------------------------------------------------------------
// layer-1 gather: h = relu(dinv*(g[d]+sum g[s]) + b), f32 out
// ---------------------------------------------------------------------------
__global__ __launch_bounds__(256) void gather_bf16(const unsigned* __restrict__ g32,
                                                   const int* __restrict__ srcs,
                                                   const int* __restrict__ row_start,
                                                   const float* __restrict__ dinv,
                                                   const float* __restrict__ b,
                                                   float* __restrict__ out, int n) {
    const int lane = threadIdx.x & 63;
    const int es   = lane >> 3;
    const int fc   = lane & 7;
    const int node = blockIdx.x * 4 + (threadIdx.x >> 6);
    if (node >= n) return;

    const int s0 = row_start[node];
    const int s1 = row_start[node + 1];

    f32x2 acc[4] = {{0.f, 0.f}, {0.f, 0.f}, {0.f, 0.f}, {0.f, 0.f}};
    gather_core(g32, srcs, s0, s1, node, es, fc, acc);
    slot_reduce(acc);

    if (es == 0) {
        float di = dinv[node];
        float4 b0 = *(const float4*)&b[fc * 8];
        float4 b1 = *(const float4*)&b[fc * 8 + 4];
        float4 o0, o1;
        o0.x = fmaxf(di * acc[0].x + b0.x, 0.f);
        o0.y = fmaxf(di * acc[0].y + b0.y, 0.f);
        o0.z = fmaxf(di * acc[1].x + b0.z, 0.f);
        o0.w = fmaxf(di * acc[1].y + b0.w, 0.f);
        o1.x = fmaxf(di * acc[2].x + b1.x, 0.f);
        o1.y = fmaxf(di * acc[2].y + b1.y, 0.f);
        o1.z = fmaxf(di * acc[3].x + b1.z, 0.f);
        o1.w = fmaxf(di * acc[3].y + b1.w, 0.f);
        *(float4*)&out[(size_t)node * 64 + fc * 8]     = o0;
        *(float4*)&out[(size_t)node * 64 + fc * 8 + 4] = o1;
    }
}

// ---------------------------------------------------------------------------
// layer-2 gather + fused MLP head:
//   h = relu(dinv*(g[d]+sum g[s]) + b2)  ->  out = relu(h@Wh1+bh1)@Wh2 + bh2
// 4 waves/block (1 node each); h staged in LDS; head on lanes 0..31/wave.
// NOTE: no early return (block-wide __syncthreads) — work is guarded instead.
// ---------------------------------------------------------------------------
__global__ __launch_bounds__(256) void gather_head(const unsigned* __restrict__ g32,
                                                   const int* __restrict__ srcs,
                                                   const int* __restrict__ row_start,
                                                   const float* __restrict__ dinv,
                                                   const float* __restrict__ b,
                                                   const float* __restrict__ Wh1,
                                                   const float* __restrict__ bh1,
                                                   const float* __restrict__ Wh2,
                                                   const float* __restrict__ bh2,
                                                   float* __restrict__ out, int n) {
    __shared__ float hs[4][64];
    __shared__ float w1s[64 * 32];
    __shared__ float w2s[64];
    __shared__ float b1s[32];
    __shared__ float b2s[2];
    const int t    = threadIdx.x;
    const int wid  = t >> 6;
    const int lane = t & 63;
    const int es   = lane >> 3;
    const int fc   = lane & 7;
    const int node = blockIdx.x * 4 + wid;
    const bool valid = node < n;

    // stage head weights (2048 + 64 + 32 + 2 floats)
#pragma unroll
    for (int i = 0; i < 2; i++) {
        int off = (i * 256 + t) * 4;
        *(float4*)&w1s[off] = *(const float4*)&Wh1[off];
    }
    if (t < 64) w2s[t] = Wh2[t];
    if (t < 32) b1s[t] = bh1[t];
    if (t < 2)  b2s[t] = bh2[t];

    if (valid) {
        const int s0 = row_start[node];
        const int s1 = row_start[node + 1];
        f32x2 acc[4] = {{0.f, 0.f}, {0.f, 0.f}, {0.f, 0.f}, {0.f, 0.f}};
        gather_core(g32, srcs, s0, s1, node, es, fc, acc);
        slot_reduce(acc);
        if (es == 0) {
            float di = dinv[node];
            float4 b0 = *(const float4*)&b[fc * 8];
            float4 b1v = *(const float4*)&b[fc * 8 + 4];
            float4 o0, o1;
            o0.x = fmaxf(di * acc[0].x + b0.x, 0.f);
            o0.y = fmaxf(di * acc[0].y + b0.y, 0.f);
            o0.z = fmaxf(di * acc[1].x + b0.z, 0.f);
            o0.w = fmaxf(di * acc[1].y + b0.w, 0.f);
            o1.x = fmaxf(di * acc[2].x + b1v.x, 0.f);
            o1.y = fmaxf(di * acc[2].y + b1v.y, 0.f);
            o1.z = fmaxf(di * acc[3].x + b1v.z, 0.f);
            o1.w = fmaxf(di * acc[3].y + b1v.w, 0.f);
            *(float4*)&hs[wid][fc * 8]     = o0;
            *(float4*)&hs[wid][fc * 8 + 4] = o1;
        }
    }
    __syncthreads();

    // head: lanes 0..31 of wave `wid` compute hid[j] for its node
    float p0 = 0.f, p1 = 0.f;
    if (valid && lane < 32) {
        const int j = lane;
        float hid = b1s[j];
#pragma unroll 8
        for (int k = 0; k < 64; k++) hid += hs[wid][k] * w1s[k * 32 + j];
        hid = fmaxf(hid, 0.f);
        p0 = hid * w2s[j * 2 + 0];
        p1 = hid * w2s[j * 2 + 1];
    }
    // reduce over all 64 lanes (lanes 32..63 contribute zeros)
#pragma unroll
    for (int off = 1; off < 64; off <<= 1) {
        p0 += __shfl_xor(p0, off, 64);
        p1 += __shfl_xor(p1, off, 64);
    }
    if (valid && lane == 0) {
        out[(size_t)node * 2 + 0] = p0 + b2s[0];
        out[(size_t)node * 2 + 1] = p1 + b2s[1];
    }
}

// ---------------------------------------------------------------------------
extern "C" void kernel_launch(void* const* d_in, const int* in_sizes, int n_in,
                              void* d_out, int out_size, void* d_ws, size_t ws_size,
                              hipStream_t stream) {
    const float* x   = (const float*)d_in[0];
    const void*  ei  = d_in[1];
    const float* W1  = (const float*)d_in[2];
    const float* b1  = (const float*)d_in[3];
    const float* W2  = (const float*)d_in[4];
    const float* b2  = (const float*)d_in[5];
    const float* Wh1 = (const float*)d_in[6];
    const float* bh1 = (const float*)d_in[7];
    const float* Wh2 = (const float*)d_in[8];
    const float* bh2 = (const float*)d_in[9];
    float* out = (float*)d_out;

    const int n = in_sizes[0] / INCH;   // 100000
    const int E = in_sizes[1] / 2;      // 3200000
    const int nbuck = (n + 255) >> BSH; // 391
    const int CAP = ((2 * (E / nbuck) + 1023) / 1024) * 1024;

    char* ws = (char*)d_ws;
    size_t off = 0;
    auto carve = [&](size_t bytes) {
        size_t p = off;
        off = (off + bytes + 255) & ~(size_t)255;
        return p;
    };
    size_t stg_bytes  = (size_t)nbuck * CAP * 4;
    size_t g32_bytes  = (size_t)n * 32 * 4;
    size_t bufA_bytes = stg_bytes > g32_bytes ? stg_bytes : g32_bytes;

    int*            flag      = (int*)(ws + carve(256));
    int*            bcur      = (int*)(ws + carve(MAXBUCK * 4));
    int*            bbase     = (int*)(ws + carve((MAXBUCK + 1) * 4));
    int*            row_start = (int*)(ws + carve((size_t)(n + 1) * 4));
    float*          dinv      = (float*)(ws + carve((size_t)n * 4));
    int*            srcs      = (int*)(ws + carve((size_t)E * 4));
    unsigned*       bufA      = (unsigned*)(ws + carve(bufA_bytes));   // staged / g32
    float*          bufB      = (float*)(ws + carve((size_t)n * HIDF * 4));
    unsigned short* whi1      = (unsigned short*)(ws + carve(8 * 4 * 64 * 8 * 2));
    unsigned short* wlo1      = (unsigned short*)(ws + carve(8 * 4 * 64 * 8 * 2));
    unsigned short* whi2      = (unsigned short*)(ws + carve(2 * 4 * 64 * 8 * 2));
    unsigned short* wlo2      = (unsigned short*)(ws + carve(2 * 4 * 64 * 8 * 2));
    (void)ws_size;

    unsigned* staged = bufA;

    detect_i64<<<1, 256, 0, stream>>>((const unsigned int*)ei, flag);

    // ---- W split (tiny) ----
    wsplit<<<8, 256, 0, stream>>>(W1, whi1, wlo1, INCH);
    wsplit<<<2, 256, 0, stream>>>(W2, whi2, wlo2, HIDF);

    // ---- CSR build (count-free multisplit) ----
    hipMemsetAsync(bcur, 0, MAXBUCK * 4, stream);
    bin_records<<<(E + CHUNK - 1) / CHUNK, 256, 0, stream>>>(ei, flag, bcur, staged, E, CAP);
    bucket_scan<<<1, MAXBUCK, 0, stream>>>(bcur, bbase, row_start, nbuck, E, n);
    bucket_finalize<<<nbuck, 256, 0, stream>>>(staged, bcur, bbase, row_start, dinv, srcs, n, CAP);

    const int mfma_grid   = (n + 63) / 64;
    const int gather_grid = (n + 3) / 4;

    // ---- layer 1 ----
    gemm_mfma<INCH><<<mfma_grid, 256, 0, stream>>>(x, whi1, wlo1, dinv, bufA, n);
    gather_bf16<<<gather_grid, 256, 0, stream>>>(bufA, srcs, row_start, dinv, b1, bufB, n);

    // ---- layer 2 + fused head ----
    gemm_mfma<HIDF><<<mfma_grid, 256, 0, stream>>>(bufB, whi2, wlo2, dinv, bufA, n);
    gather_head<<<gather_grid, 256, 0, stream>>>(bufA, srcs, row_start, dinv, b2,
                                                 Wh1, bh1, Wh2, bh2, out, n);
}

// Round 14
// 266.320 us; speedup vs baseline: 1.0459x; 1.0459x over previous
//
#include <hip/hip_runtime.h>

#define INCH 256
#define HIDF 64
#define BSH 8              // 256 nodes per bucket
#define MAXBUCK 512        // supports n up to 131072
#define CHUNK 4096         // edges per bin_records block

typedef __attribute__((ext_vector_type(8))) short short8v;  // 8 bf16 (4 VGPRs)
typedef __attribute__((ext_vector_type(4))) float f32x4;
typedef __attribute__((ext_vector_type(2))) float f32x2;

// ---------------------------------------------------------------------------
// edge dtype sniffer
// ---------------------------------------------------------------------------
__global__ void detect_i64(const unsigned int* __restrict__ ei, int* __restrict__ flag) {
    __shared__ int nonzero;
    if (threadIdx.x == 0) nonzero = 0;
    __syncthreads();
    if (ei[2 * (size_t)threadIdx.x + 1] != 0u) nonzero = 1;
    __syncthreads();
    if (threadIdx.x == 0) *flag = (nonzero == 0) ? 1 : 0;
}

__device__ __forceinline__ int edge_at(const void* ei, int is64, long long i) {
    if (is64) return (int)((const long long*)ei)[i];
    return ((const int*)ei)[i];
}

// round-to-nearest-even f32 -> bf16 (as u16 in low bits)
__device__ __forceinline__ unsigned bf16rne(float f) {
    unsigned u = __float_as_uint(f);
    return (u + 0x7fffu + ((u >> 16) & 1u)) >> 16;
}

// ---------------------------------------------------------------------------
// CSR build (count-free multisplit) — unchanged from round 12
// ---------------------------------------------------------------------------
__global__ __launch_bounds__(256) void bin_records(const void* __restrict__ ei,
                                                   const int* __restrict__ flag,
                                                   int* __restrict__ bcur,
                                                   unsigned* __restrict__ staged,
                                                   int E, int CAP) {
    __shared__ int cnt[MAXBUCK];
    __shared__ int cur[MAXBUCK];
    const int t = threadIdx.x;
    const int is64 = *flag;
    const long long base = (long long)blockIdx.x * CHUNK;

    for (int b = t; b < MAXBUCK; b += 256) cnt[b] = 0;
    __syncthreads();

    int sr[16], dr[16];
#pragma unroll
    for (int i = 0; i < 16; i++) {
        long long e = base + (long long)i * 256 + t;
        if (e < E) {
            sr[i] = edge_at(ei, is64, e);
            dr[i] = edge_at(ei, is64, (long long)E + e);
            atomicAdd(&cnt[dr[i] >> BSH], 1);
        } else {
            dr[i] = -1;
        }
    }
    __syncthreads();

    for (int b = t; b < MAXBUCK; b += 256)
        if (cnt[b]) cur[b] = b * CAP + atomicAdd(&bcur[b], cnt[b]);
    __syncthreads();

#pragma unroll
    for (int i = 0; i < 16; i++) {
        if (dr[i] >= 0) {
            int gpos = atomicAdd(&cur[dr[i] >> BSH], 1);
            staged[gpos] = (unsigned)sr[i] | ((unsigned)(dr[i] & 255) << 24);
        }
    }
}

__global__ void bucket_scan(const int* __restrict__ bcur, int* __restrict__ bbase,
                            int* __restrict__ row_start, int nbuck, int E, int n) {
    __shared__ int s[MAXBUCK];
    int t = threadIdx.x;
    int v = (t < nbuck) ? bcur[t] : 0;
    s[t] = v;
    __syncthreads();
    for (int off = 1; off < MAXBUCK; off <<= 1) {
        int add = (t >= off) ? s[t - off] : 0;
        __syncthreads();
        s[t] += add;
        __syncthreads();
    }
    if (t < nbuck) bbase[t] = s[t] - v;
    if (t == 0) {
        bbase[nbuck] = E;
        row_start[n] = E;
    }
}

__global__ __launch_bounds__(256) void bucket_finalize(const unsigned* __restrict__ staged,
                                                       const int* __restrict__ bcnts,
                                                       const int* __restrict__ bbase,
                                                       int* __restrict__ row_start,
                                                       float* __restrict__ dinv,
                                                       int* __restrict__ srcs,
                                                       int n, int CAP) {
    __shared__ int cnt[256];
    __shared__ int sc[256];
    __shared__ int cur[256];
    const int b  = blockIdx.x;
    const int t  = threadIdx.x;
    const int d0 = b << BSH;
    const int r0 = bbase[b];
    const int cb = bcnts[b];
    const size_t sb = (size_t)b * CAP;

    cnt[t] = 0;
    __syncthreads();
    for (int j = t; j < cb; j += 256) {
        unsigned rec = staged[sb + j];
        atomicAdd(&cnt[rec >> 24], 1);
    }
    __syncthreads();

    int v = cnt[t];
    sc[t] = v;
    __syncthreads();
    for (int off = 1; off < 256; off <<= 1) {
        int add = (t >= off) ? sc[t - off] : 0;
        __syncthreads();
        sc[t] += add;
        __syncthreads();
    }
    int ex = sc[t] - v;

    int node = d0 + t;
    if (node < n) {
        row_start[node] = r0 + ex;
        dinv[node] = rsqrtf((float)v + 1.0f);
    }
    cur[t] = r0 + ex;
    __syncthreads();

    for (int j = t; j < cb; j += 256) {
        unsigned rec = staged[sb + j];
        int pos = atomicAdd(&cur[rec >> 24], 1);
        srcs[pos] = (int)(rec & 0xffffffu);
    }
}

// ---------------------------------------------------------------------------
// W split+swizzle — unchanged
// ---------------------------------------------------------------------------
__global__ void wsplit(const float* __restrict__ W, unsigned short* __restrict__ whi,
                       unsigned short* __restrict__ wlo, int K) {
    int tid = blockIdx.x * 256 + threadIdx.x;
    int total = (K / 32) * 4 * 64;
    if (tid >= total) return;
    int lane = tid & 63;
    int nf   = (tid >> 6) & 3;
    int ks   = tid >> 8;
    int col  = nf * 16 + (lane & 15);
    int k0   = ks * 32 + (lane >> 4) * 8;
#pragma unroll
    for (int i = 0; i < 8; i++) {
        float w = W[(size_t)(k0 + i) * 64 + col];
        unsigned u = __float_as_uint(w);
        float hif = __uint_as_float(u & 0xffff0000u);
        whi[(size_t)tid * 8 + i] = (unsigned short)(u >> 16);
        wlo[(size_t)tid * 8 + i] = (unsigned short)(__float_as_uint(w - hif) >> 16);
    }
}

// ---------------------------------------------------------------------------
// split-bf16 MFMA GEMM — unchanged
// ---------------------------------------------------------------------------
template <int K>
__global__ __launch_bounds__(256) void gemm_mfma(const float* __restrict__ X,
                                                 const unsigned short* __restrict__ whi,
                                                 const unsigned short* __restrict__ wlo,
                                                 const float* __restrict__ dinv,
                                                 unsigned* __restrict__ Y, int n) {
    __shared__ unsigned tile[64 * 36];
    __shared__ float dl[64];
    const int t    = threadIdx.x;
    const int wid  = t >> 6;
    const int lane = t & 63;
    const int r0   = blockIdx.x * 64;

    if (t < 64) dl[t] = (r0 + t < n) ? dinv[r0 + t] : 0.f;
    __syncthreads();

    const int mrow = lane & 15;
    const int kg   = (lane >> 4) * 8;
    const int row  = r0 + wid * 16 + mrow;
    const bool rv  = row < n;

    f32x4 acc0 = {0.f, 0.f, 0.f, 0.f};
    f32x4 acc1 = {0.f, 0.f, 0.f, 0.f};
    f32x4 acc2 = {0.f, 0.f, 0.f, 0.f};
    f32x4 acc3 = {0.f, 0.f, 0.f, 0.f};

    for (int ks = 0; ks < K / 32; ks++) {
        float4 a0 = {0.f, 0.f, 0.f, 0.f}, a1 = {0.f, 0.f, 0.f, 0.f};
        if (rv) {
            const float* xp = &X[(size_t)row * K + ks * 32 + kg];
            a0 = *(const float4*)xp;
            a1 = *(const float4*)(xp + 4);
        }
        float av[8] = {a0.x, a0.y, a0.z, a0.w, a1.x, a1.y, a1.z, a1.w};
        short8v ahi, alo;
#pragma unroll
        for (int i = 0; i < 8; i++) {
            unsigned u = __float_as_uint(av[i]);
            ahi[i] = (short)(u >> 16);
            float hif = __uint_as_float(u & 0xffff0000u);
            alo[i] = (short)(__float_as_uint(av[i] - hif) >> 16);
        }
        const size_t bbase = ((size_t)ks * 4 * 64 + lane) * 8;
        short8v bh0 = *(const short8v*)&whi[bbase + 0 * 512];
        short8v bh1 = *(const short8v*)&whi[bbase + 1 * 512];
        short8v bh2 = *(const short8v*)&whi[bbase + 2 * 512];
        short8v bh3 = *(const short8v*)&whi[bbase + 3 * 512];
        short8v bl0 = *(const short8v*)&wlo[bbase + 0 * 512];
        short8v bl1 = *(const short8v*)&wlo[bbase + 1 * 512];
        short8v bl2 = *(const short8v*)&wlo[bbase + 2 * 512];
        short8v bl3 = *(const short8v*)&wlo[bbase + 3 * 512];

        acc0 = __builtin_amdgcn_mfma_f32_16x16x32_bf16(ahi, bh0, acc0, 0, 0, 0);
        acc1 = __builtin_amdgcn_mfma_f32_16x16x32_bf16(ahi, bh1, acc1, 0, 0, 0);
        acc2 = __builtin_amdgcn_mfma_f32_16x16x32_bf16(ahi, bh2, acc2, 0, 0, 0);
        acc3 = __builtin_amdgcn_mfma_f32_16x16x32_bf16(ahi, bh3, acc3, 0, 0, 0);
        acc0 = __builtin_amdgcn_mfma_f32_16x16x32_bf16(alo, bh0, acc0, 0, 0, 0);
        acc1 = __builtin_amdgcn_mfma_f32_16x16x32_bf16(alo, bh1, acc1, 0, 0, 0);
        acc2 = __builtin_amdgcn_mfma_f32_16x16x32_bf16(alo, bh2, acc2, 0, 0, 0);
        acc3 = __builtin_amdgcn_mfma_f32_16x16x32_bf16(alo, bh3, acc3, 0, 0, 0);
        acc0 = __builtin_amdgcn_mfma_f32_16x16x32_bf16(ahi, bl0, acc0, 0, 0, 0);
        acc1 = __builtin_amdgcn_mfma_f32_16x16x32_bf16(ahi, bl1, acc1, 0, 0, 0);
        acc2 = __builtin_amdgcn_mfma_f32_16x16x32_bf16(ahi, bl2, acc2, 0, 0, 0);
        acc3 = __builtin_amdgcn_mfma_f32_16x16x32_bf16(ahi, bl3, acc3, 0, 0, 0);
    }

    const int c15 = lane & 15;
#pragma unroll
    for (int nf = 0; nf < 4; nf++) {
        f32x4 a = (nf == 0) ? acc0 : (nf == 1) ? acc1 : (nf == 2) ? acc2 : acc3;
#pragma unroll
        for (int r = 0; r < 4; r++) {
            int m = (lane >> 4) * 4 + r;
            float v = a[r] * dl[wid * 16 + m];
            float pv = __shfl_xor(v, 1, 64);
            if (!(lane & 1)) {
                unsigned u = bf16rne(v) | (bf16rne(pv) << 16);
                tile[(wid * 16 + m) * 36 + nf * 8 + (c15 >> 1)] = u;
            }
        }
    }
    __syncthreads();

    {
        int lrow = t >> 2;
        int cb   = (t & 3) * 8;
        if (r0 + lrow < n) {
            uint4 w0 = *(const uint4*)&tile[lrow * 36 + cb];
            uint4 w1 = *(const uint4*)&tile[lrow * 36 + cb + 4];
            *(uint4*)&Y[(size_t)(r0 + lrow) * 32 + cb]     = w0;
            *(uint4*)&Y[(size_t)(r0 + lrow) * 32 + cb + 4] = w1;
        }
    }
}

// ---------------------------------------------------------------------------
// gather: wave = 1 node; lane = (edge-slot es, uint4-chunk fc); 4-deep
// row-load pipeline; packed-f32 accumulate.
// h[d] = relu(dinv[d]*(g[d]+sum g[s]) + b)
// ---------------------------------------------------------------------------
__device__ __forceinline__ void acc_pair(f32x2& a, unsigned w) {
    f32x2 v;
    v.x = __uint_as_float(w << 16);
    v.y = __uint_as_float(w & 0xffff0000u);
    a += v;   // v_pk_add_f32
}

__device__ __forceinline__ void acc_u4(f32x2* acc, uint4 u) {
    acc_pair(acc[0], u.x);
    acc_pair(acc[1], u.y);
    acc_pair(acc[2], u.z);
    acc_pair(acc[3], u.w);
}

__global__ __launch_bounds__(256) void gather_bf16(const unsigned* __restrict__ g32,
                                                   const int* __restrict__ srcs,
                                                   const int* __restrict__ row_start,
                                                   const float* __restrict__ dinv,
                                                   const float* __restrict__ b,
                                                   float* __restrict__ out, int n) {
    const int lane = threadIdx.x & 63;
    const int es   = lane >> 3;
    const int fc   = lane & 7;
    const int node = blockIdx.x * 4 + (threadIdx.x >> 6);
    if (node >= n) return;

    const int s0 = row_start[node];
    const int s1 = row_start[node + 1];

    f32x2 acc[4] = {{0.f, 0.f}, {0.f, 0.f}, {0.f, 0.f}, {0.f, 0.f}};

    if (es == 0) acc_u4(acc, *(const uint4*)&g32[(size_t)node * 32 + fc * 4]);

    int j = s0 + es;
    for (; j + 24 < s1; j += 32) {       // 4 rows in flight
        int a0 = srcs[j];
        int a1 = srcs[j + 8];
        int a2 = srcs[j + 16];
        int a3 = srcs[j + 24];
        uint4 u0 = *(const uint4*)&g32[(size_t)a0 * 32 + fc * 4];
        uint4 u1 = *(const uint4*)&g32[(size_t)a1 * 32 + fc * 4];
        uint4 u2 = *(const uint4*)&g32[(size_t)a2 * 32 + fc * 4];
        uint4 u3 = *(const uint4*)&g32[(size_t)a3 * 32 + fc * 4];
        acc_u4(acc, u0);
        acc_u4(acc, u1);
        acc_u4(acc, u2);
        acc_u4(acc, u3);
    }
    for (; j + 8 < s1; j += 16) {        // 2 rows in flight
        int a0 = srcs[j];
        int a1 = srcs[j + 8];
        uint4 u0 = *(const uint4*)&g32[(size_t)a0 * 32 + fc * 4];
        uint4 u1 = *(const uint4*)&g32[(size_t)a1 * 32 + fc * 4];
        acc_u4(acc, u0);
        acc_u4(acc, u1);
    }
    if (j < s1) acc_u4(acc, *(const uint4*)&g32[(size_t)srcs[j] * 32 + fc * 4]);

    // reduce across the 8 edge slots (lane bits 3,4,5)
#pragma unroll
    for (int q = 0; q < 4; q++) {
        acc[q].x += __shfl_xor(acc[q].x, 8, 64);
        acc[q].y += __shfl_xor(acc[q].y, 8, 64);
        acc[q].x += __shfl_xor(acc[q].x, 16, 64);
        acc[q].y += __shfl_xor(acc[q].y, 16, 64);
        acc[q].x += __shfl_xor(acc[q].x, 32, 64);
        acc[q].y += __shfl_xor(acc[q].y, 32, 64);
    }

    if (es == 0) {
        float di = dinv[node];
        float4 b0 = *(const float4*)&b[fc * 8];
        float4 b1 = *(const float4*)&b[fc * 8 + 4];
        float4 o0, o1;
        o0.x = fmaxf(di * acc[0].x + b0.x, 0.f);
        o0.y = fmaxf(di * acc[0].y + b0.y, 0.f);
        o0.z = fmaxf(di * acc[1].x + b0.z, 0.f);
        o0.w = fmaxf(di * acc[1].y + b0.w, 0.f);
        o1.x = fmaxf(di * acc[2].x + b1.x, 0.f);
        o1.y = fmaxf(di * acc[2].y + b1.y, 0.f);
        o1.z = fmaxf(di * acc[3].x + b1.z, 0.f);
        o1.w = fmaxf(di * acc[3].y + b1.w, 0.f);
        *(float4*)&out[(size_t)node * 64 + fc * 8]     = o0;
        *(float4*)&out[(size_t)node * 64 + fc * 8 + 4] = o1;
    }
}

// ---------------------------------------------------------------------------
// fused MLP head (standalone, round-12 form): out = relu(h@Wh1+bh1)@Wh2+bh2
// ---------------------------------------------------------------------------
__global__ __launch_bounds__(128) void head_kernel(const float* __restrict__ h,
                                                   const float* __restrict__ Wh1,
                                                   const float* __restrict__ bh1,
                                                   const float* __restrict__ Wh2,
                                                   const float* __restrict__ bh2,
                                                   float* __restrict__ out, int n) {
    __shared__ float xs[128 * 65];
    __shared__ float w1s[64 * 32];
    __shared__ float w2s[64];
    __shared__ float b1s[32];
    __shared__ float b2s[2];
    const int t  = threadIdx.x;
    const int r0 = blockIdx.x * 128;

#pragma unroll
    for (int i = 0; i < 4; i++) {
        int off = (i * 128 + t) * 4;
        *(float4*)&w1s[off] = *(const float4*)&Wh1[off];
    }
    if (t < 64) w2s[t] = Wh2[t];
    if (t < 32) b1s[t] = bh1[t];
    if (t < 2)  b2s[t] = bh2[t];

#pragma unroll
    for (int i = 0; i < 16; i++) {
        int linear = i * 128 + t;
        int row = linear >> 4;
        int k4  = linear & 15;
        float4 v = {0.f, 0.f, 0.f, 0.f};
        int gr = r0 + row;
        if (gr < n) v = *(const float4*)&h[(size_t)gr * 64 + k4 * 4];
        int base = row * 65 + k4 * 4;
        xs[base + 0] = v.x;
        xs[base + 1] = v.y;
        xs[base + 2] = v.z;
        xs[base + 3] = v.w;
    }
    __syncthreads();

    float hid[32];
#pragma unroll
    for (int j = 0; j < 32; j++) hid[j] = b1s[j];

#pragma unroll 4
    for (int k = 0; k < 64; k++) {
        float xv = xs[t * 65 + k];
#pragma unroll
        for (int j4 = 0; j4 < 8; j4++) {
            float4 w = *(const float4*)&w1s[k * 32 + j4 * 4];
            hid[j4 * 4 + 0] += xv * w.x;
            hid[j4 * 4 + 1] += xv * w.y;
            hid[j4 * 4 + 2] += xv * w.z;
            hid[j4 * 4 + 3] += xv * w.w;
        }
    }

    float o0 = b2s[0], o1 = b2s[1];
#pragma unroll
    for (int j = 0; j < 32; j++) {
        float hv = fmaxf(hid[j], 0.f);
        o0 += hv * w2s[j * 2 + 0];
        o1 += hv * w2s[j * 2 + 1];
    }
    int gr = r0 + t;
    if (gr < n) {
        out[(size_t)gr * 2 + 0] = o0;
        out[(size_t)gr * 2 + 1] = o1;
    }
}

// ---------------------------------------------------------------------------
extern "C" void kernel_launch(void* const* d_in, const int* in_sizes, int n_in,
                              void* d_out, int out_size, void* d_ws, size_t ws_size,
                              hipStream_t stream) {
    const float* x   = (const float*)d_in[0];
    const void*  ei  = d_in[1];
    const float* W1  = (const float*)d_in[2];
    const float* b1  = (const float*)d_in[3];
    const float* W2  = (const float*)d_in[4];
    const float* b2  = (const float*)d_in[5];
    const float* Wh1 = (const float*)d_in[6];
    const float* bh1 = (const float*)d_in[7];
    const float* Wh2 = (const float*)d_in[8];
    const float* bh2 = (const float*)d_in[9];
    float* out = (float*)d_out;

    const int n = in_sizes[0] / INCH;   // 100000
    const int E = in_sizes[1] / 2;      // 3200000
    const int nbuck = (n + 255) >> BSH; // 391
    const int CAP = ((2 * (E / nbuck) + 1023) / 1024) * 1024;

    char* ws = (char*)d_ws;
    size_t off = 0;
    auto carve = [&](size_t bytes) {
        size_t p = off;
        off = (off + bytes + 255) & ~(size_t)255;
        return p;
    };
    size_t stg_bytes  = (size_t)nbuck * CAP * 4;
    size_t g32_bytes  = (size_t)n * 32 * 4;
    size_t bufA_bytes = stg_bytes > g32_bytes ? stg_bytes : g32_bytes;

    int*            flag      = (int*)(ws + carve(256));
    int*            bcur      = (int*)(ws + carve(MAXBUCK * 4));
    int*            bbase     = (int*)(ws + carve((MAXBUCK + 1) * 4));
    int*            row_start = (int*)(ws + carve((size_t)(n + 1) * 4));
    float*          dinv      = (float*)(ws + carve((size_t)n * 4));
    int*            srcs      = (int*)(ws + carve((size_t)E * 4));
    unsigned*       bufA      = (unsigned*)(ws + carve(bufA_bytes));   // staged / g32
    float*          bufB      = (float*)(ws + carve((size_t)n * HIDF * 4));
    unsigned short* whi1      = (unsigned short*)(ws + carve(8 * 4 * 64 * 8 * 2));
    unsigned short* wlo1      = (unsigned short*)(ws + carve(8 * 4 * 64 * 8 * 2));
    unsigned short* whi2      = (unsigned short*)(ws + carve(2 * 4 * 64 * 8 * 2));
    unsigned short* wlo2      = (unsigned short*)(ws + carve(2 * 4 * 64 * 8 * 2));
    (void)ws_size;

    unsigned* staged = bufA;

    detect_i64<<<1, 256, 0, stream>>>((const unsigned int*)ei, flag);

    // ---- W split (tiny) ----
    wsplit<<<8, 256, 0, stream>>>(W1, whi1, wlo1, INCH);
    wsplit<<<2, 256, 0, stream>>>(W2, whi2, wlo2, HIDF);

    // ---- CSR build (count-free multisplit) ----
    hipMemsetAsync(bcur, 0, MAXBUCK * 4, stream);
    bin_records<<<(E + CHUNK - 1) / CHUNK, 256, 0, stream>>>(ei, flag, bcur, staged, E, CAP);
    bucket_scan<<<1, MAXBUCK, 0, stream>>>(bcur, bbase, row_start, nbuck, E, n);
    bucket_finalize<<<nbuck, 256, 0, stream>>>(staged, bcur, bbase, row_start, dinv, srcs, n, CAP);

    const int mfma_grid   = (n + 63) / 64;
    const int gather_grid = (n + 3) / 4;

    // ---- layer 1 ----
    gemm_mfma<INCH><<<mfma_grid, 256, 0, stream>>>(x, whi1, wlo1, dinv, bufA, n);
    gather_bf16<<<gather_grid, 256, 0, stream>>>(bufA, srcs, row_start, dinv, b1, bufB, n);

    // ---- layer 2 ----
    gemm_mfma<HIDF><<<mfma_grid, 256, 0, stream>>>(bufB, whi2, wlo2, dinv, bufA, n);
    gather_bf16<<<gather_grid, 256, 0, stream>>>(bufA, srcs, row_start, dinv, b2, bufB, n);

    // ---- head ----
    head_kernel<<<(n + 127) / 128, 128, 0, stream>>>(bufB, Wh1, bh1, Wh2, bh2, out, n);
}

// Round 15
// 252.414 us; speedup vs baseline: 1.1035x; 1.0551x over previous
//
#include <hip/hip_runtime.h>

#define INCH 256
#define HIDF 64
#define BSH 8              // 256 nodes per bucket
#define MAXBUCK 512        // supports n up to 131072
#define CHUNK 8192         // edges per bin_records block (512 threads x 16)

typedef __attribute__((ext_vector_type(8))) short short8v;  // 8 bf16 (4 VGPRs)
typedef __attribute__((ext_vector_type(4))) float f32x4;
typedef __attribute__((ext_vector_type(2))) float f32x2;

__device__ __forceinline__ int edge_at(const void* ei, int is64, long long i) {
    if (is64) return (int)((const long long*)ei)[i];
    return ((const int*)ei)[i];
}

// round-to-nearest-even f32 -> bf16 (as u16 in low bits)
__device__ __forceinline__ unsigned bf16rne(float f) {
    unsigned u = __float_as_uint(f);
    return (u + 0x7fffu + ((u >> 16) & 1u)) >> 16;
}

// ---------------------------------------------------------------------------
// prep: blocks 0-7 split W1, blocks 8-9 split W2 (bf16 hi/lo in MFMA B-frag
// layout), block 10 = edge-dtype sniffer + bcur zeroing. One launch.
// ---------------------------------------------------------------------------
__device__ __forceinline__ void wsplit_body(const float* __restrict__ W,
                                            unsigned short* __restrict__ whi,
                                            unsigned short* __restrict__ wlo,
                                            int K, int tid) {
    int total = (K / 32) * 4 * 64;
    if (tid >= total) return;
    int lane = tid & 63;
    int nf   = (tid >> 6) & 3;
    int ks   = tid >> 8;
    int col  = nf * 16 + (lane & 15);
    int k0   = ks * 32 + (lane >> 4) * 8;
#pragma unroll
    for (int i = 0; i < 8; i++) {
        float w = W[(size_t)(k0 + i) * 64 + col];
        unsigned u = __float_as_uint(w);
        float hif = __uint_as_float(u & 0xffff0000u);
        whi[(size_t)tid * 8 + i] = (unsigned short)(u >> 16);
        wlo[(size_t)tid * 8 + i] = (unsigned short)(__float_as_uint(w - hif) >> 16);
    }
}

__global__ __launch_bounds__(256) void prep_kernel(const float* __restrict__ W1,
                                                   unsigned short* __restrict__ whi1,
                                                   unsigned short* __restrict__ wlo1,
                                                   const float* __restrict__ W2,
                                                   unsigned short* __restrict__ whi2,
                                                   unsigned short* __restrict__ wlo2,
                                                   const unsigned* __restrict__ ei,
                                                   int* __restrict__ flag,
                                                   int* __restrict__ bcur) {
    const int blk = blockIdx.x;
    const int t   = threadIdx.x;
    if (blk < 8) {
        wsplit_body(W1, whi1, wlo1, INCH, blk * 256 + t);
    } else if (blk < 10) {
        wsplit_body(W2, whi2, wlo2, HIDF, (blk - 8) * 256 + t);
    } else {
        __shared__ int nonzero;
        if (t == 0) nonzero = 0;
        __syncthreads();
        if (ei[2 * (size_t)t + 1] != 0u) nonzero = 1;
        __syncthreads();
        if (t == 0) *flag = (nonzero == 0) ? 1 : 0;
        bcur[t] = 0;
        bcur[t + 256] = 0;
    }
}

// ---------------------------------------------------------------------------
// CSR build (count-free multisplit): 512-thread blocks, 8192 edges/block ->
// ~21-record contiguous runs per bucket per block (84B), half the reserve
// atomics of the 4096 version. staged rec = src | (dst&255)<<24.
// ---------------------------------------------------------------------------
__global__ __launch_bounds__(512) void bin_records(const void* __restrict__ ei,
                                                   const int* __restrict__ flag,
                                                   int* __restrict__ bcur,
                                                   unsigned* __restrict__ staged,
                                                   int E, int CAP) {
    __shared__ int cnt[MAXBUCK];
    __shared__ int cur[MAXBUCK];
    const int t = threadIdx.x;
    const int is64 = *flag;
    const long long base = (long long)blockIdx.x * CHUNK;

    for (int b = t; b < MAXBUCK; b += 512) cnt[b] = 0;
    __syncthreads();

    int sr[16], dr[16];
#pragma unroll
    for (int i = 0; i < 16; i++) {
        long long e = base + (long long)i * 512 + t;
        if (e < E) {
            sr[i] = edge_at(ei, is64, e);
            dr[i] = edge_at(ei, is64, (long long)E + e);
            atomicAdd(&cnt[dr[i] >> BSH], 1);
        } else {
            dr[i] = -1;
        }
    }
    __syncthreads();

    for (int b = t; b < MAXBUCK; b += 512)
        if (cnt[b]) cur[b] = b * CAP + atomicAdd(&bcur[b], cnt[b]);
    __syncthreads();

#pragma unroll
    for (int i = 0; i < 16; i++) {
        if (dr[i] >= 0) {
            int gpos = atomicAdd(&cur[dr[i] >> BSH], 1);
            staged[gpos] = (unsigned)sr[i] | ((unsigned)(dr[i] & 255) << 24);
        }
    }
}

__global__ void bucket_scan(const int* __restrict__ bcur, int* __restrict__ bbase,
                            int* __restrict__ row_start, int nbuck, int E, int n) {
    __shared__ int s[MAXBUCK];
    int t = threadIdx.x;
    int v = (t < nbuck) ? bcur[t] : 0;
    s[t] = v;
    __syncthreads();
    for (int off = 1; off < MAXBUCK; off <<= 1) {
        int add = (t >= off) ? s[t - off] : 0;
        __syncthreads();
        s[t] += add;
        __syncthreads();
    }
    if (t < nbuck) bbase[t] = s[t] - v;
    if (t == 0) {
        bbase[nbuck] = E;
        row_start[n] = E;
    }
}

__global__ __launch_bounds__(256) void bucket_finalize(const unsigned* __restrict__ staged,
                                                       const int* __restrict__ bcnts,
                                                       const int* __restrict__ bbase,
                                                       int* __restrict__ row_start,
                                                       float* __restrict__ dinv,
                                                       int* __restrict__ srcs,
                                                       int n, int CAP) {
    __shared__ int cnt[256];
    __shared__ int sc[256];
    __shared__ int cur[256];
    const int b  = blockIdx.x;
    const int t  = threadIdx.x;
    const int d0 = b << BSH;
    const int r0 = bbase[b];
    const int cb = bcnts[b];
    const size_t sb = (size_t)b * CAP;

    cnt[t] = 0;
    __syncthreads();
    for (int j = t; j < cb; j += 256) {
        unsigned rec = staged[sb + j];
        atomicAdd(&cnt[rec >> 24], 1);
    }
    __syncthreads();

    int v = cnt[t];
    sc[t] = v;
    __syncthreads();
    for (int off = 1; off < 256; off <<= 1) {
        int add = (t >= off) ? sc[t - off] : 0;
        __syncthreads();
        sc[t] += add;
        __syncthreads();
    }
    int ex = sc[t] - v;

    int node = d0 + t;
    if (node < n) {
        row_start[node] = r0 + ex;
        dinv[node] = rsqrtf((float)v + 1.0f);
    }
    cur[t] = r0 + ex;
    __syncthreads();

    for (int j = t; j < cb; j += 256) {
        unsigned rec = staged[sb + j];
        int pos = atomicAdd(&cur[rec >> 24], 1);
        srcs[pos] = (int)(rec & 0xffffffu);
    }
}

// ---------------------------------------------------------------------------
// split-bf16 MFMA GEMM — unchanged
// ---------------------------------------------------------------------------
template <int K>
__global__ __launch_bounds__(256) void gemm_mfma(const float* __restrict__ X,
                                                 const unsigned short* __restrict__ whi,
                                                 const unsigned short* __restrict__ wlo,
                                                 const float* __restrict__ dinv,
                                                 unsigned* __restrict__ Y, int n) {
    __shared__ unsigned tile[64 * 36];
    __shared__ float dl[64];
    const int t    = threadIdx.x;
    const int wid  = t >> 6;
    const int lane = t & 63;
    const int r0   = blockIdx.x * 64;

    if (t < 64) dl[t] = (r0 + t < n) ? dinv[r0 + t] : 0.f;
    __syncthreads();

    const int mrow = lane & 15;
    const int kg   = (lane >> 4) * 8;
    const int row  = r0 + wid * 16 + mrow;
    const bool rv  = row < n;

    f32x4 acc0 = {0.f, 0.f, 0.f, 0.f};
    f32x4 acc1 = {0.f, 0.f, 0.f, 0.f};
    f32x4 acc2 = {0.f, 0.f, 0.f, 0.f};
    f32x4 acc3 = {0.f, 0.f, 0.f, 0.f};

    for (int ks = 0; ks < K / 32; ks++) {
        float4 a0 = {0.f, 0.f, 0.f, 0.f}, a1 = {0.f, 0.f, 0.f, 0.f};
        if (rv) {
            const float* xp = &X[(size_t)row * K + ks * 32 + kg];
            a0 = *(const float4*)xp;
            a1 = *(const float4*)(xp + 4);
        }
        float av[8] = {a0.x, a0.y, a0.z, a0.w, a1.x, a1.y, a1.z, a1.w};
        short8v ahi, alo;
#pragma unroll
        for (int i = 0; i < 8; i++) {
            unsigned u = __float_as_uint(av[i]);
            ahi[i] = (short)(u >> 16);
            float hif = __uint_as_float(u & 0xffff0000u);
            alo[i] = (short)(__float_as_uint(av[i] - hif) >> 16);
        }
        const size_t bbase = ((size_t)ks * 4 * 64 + lane) * 8;
        short8v bh0 = *(const short8v*)&whi[bbase + 0 * 512];
        short8v bh1 = *(const short8v*)&whi[bbase + 1 * 512];
        short8v bh2 = *(const short8v*)&whi[bbase + 2 * 512];
        short8v bh3 = *(const short8v*)&whi[bbase + 3 * 512];
        short8v bl0 = *(const short8v*)&wlo[bbase + 0 * 512];
        short8v bl1 = *(const short8v*)&wlo[bbase + 1 * 512];
        short8v bl2 = *(const short8v*)&wlo[bbase + 2 * 512];
        short8v bl3 = *(const short8v*)&wlo[bbase + 3 * 512];

        acc0 = __builtin_amdgcn_mfma_f32_16x16x32_bf16(ahi, bh0, acc0, 0, 0, 0);
        acc1 = __builtin_amdgcn_mfma_f32_16x16x32_bf16(ahi, bh1, acc1, 0, 0, 0);
        acc2 = __builtin_amdgcn_mfma_f32_16x16x32_bf16(ahi, bh2, acc2, 0, 0, 0);
        acc3 = __builtin_amdgcn_mfma_f32_16x16x32_bf16(ahi, bh3, acc3, 0, 0, 0);
        acc0 = __builtin_amdgcn_mfma_f32_16x16x32_bf16(alo, bh0, acc0, 0, 0, 0);
        acc1 = __builtin_amdgcn_mfma_f32_16x16x32_bf16(alo, bh1, acc1, 0, 0, 0);
        acc2 = __builtin_amdgcn_mfma_f32_16x16x32_bf16(alo, bh2, acc2, 0, 0, 0);
        acc3 = __builtin_amdgcn_mfma_f32_16x16x32_bf16(alo, bh3, acc3, 0, 0, 0);
        acc0 = __builtin_amdgcn_mfma_f32_16x16x32_bf16(ahi, bl0, acc0, 0, 0, 0);
        acc1 = __builtin_amdgcn_mfma_f32_16x16x32_bf16(ahi, bl1, acc1, 0, 0, 0);
        acc2 = __builtin_amdgcn_mfma_f32_16x16x32_bf16(ahi, bl2, acc2, 0, 0, 0);
        acc3 = __builtin_amdgcn_mfma_f32_16x16x32_bf16(ahi, bl3, acc3, 0, 0, 0);
    }

    const int c15 = lane & 15;
#pragma unroll
    for (int nf = 0; nf < 4; nf++) {
        f32x4 a = (nf == 0) ? acc0 : (nf == 1) ? acc1 : (nf == 2) ? acc2 : acc3;
#pragma unroll
        for (int r = 0; r < 4; r++) {
            int m = (lane >> 4) * 4 + r;
            float v = a[r] * dl[wid * 16 + m];
            float pv = __shfl_xor(v, 1, 64);
            if (!(lane & 1)) {
                unsigned u = bf16rne(v) | (bf16rne(pv) << 16);
                tile[(wid * 16 + m) * 36 + nf * 8 + (c15 >> 1)] = u;
            }
        }
    }
    __syncthreads();

    {
        int lrow = t >> 2;
        int cb   = (t & 3) * 8;
        if (r0 + lrow < n) {
            uint4 w0 = *(const uint4*)&tile[lrow * 36 + cb];
            uint4 w1 = *(const uint4*)&tile[lrow * 36 + cb + 4];
            *(uint4*)&Y[(size_t)(r0 + lrow) * 32 + cb]     = w0;
            *(uint4*)&Y[(size_t)(r0 + lrow) * 32 + cb + 4] = w1;
        }
    }
}

// ---------------------------------------------------------------------------
// gather — unchanged (confirmed at L3 random-access floor)
// ---------------------------------------------------------------------------
__device__ __forceinline__ void acc_pair(f32x2& a, unsigned w) {
    f32x2 v;
    v.x = __uint_as_float(w << 16);
    v.y = __uint_as_float(w & 0xffff0000u);
    a += v;
}

__device__ __forceinline__ void acc_u4(f32x2* acc, uint4 u) {
    acc_pair(acc[0], u.x);
    acc_pair(acc[1], u.y);
    acc_pair(acc[2], u.z);
    acc_pair(acc[3], u.w);
}

__global__ __launch_bounds__(256) void gather_bf16(const unsigned* __restrict__ g32,
                                                   const int* __restrict__ srcs,
                                                   const int* __restrict__ row_start,
                                                   const float* __restrict__ dinv,
                                                   const float* __restrict__ b,
                                                   float* __restrict__ out, int n) {
    const int lane = threadIdx.x & 63;
    const int es   = lane >> 3;
    const int fc   = lane & 7;
    const int node = blockIdx.x * 4 + (threadIdx.x >> 6);
    if (node >= n) return;

    const int s0 = row_start[node];
    const int s1 = row_start[node + 1];

    f32x2 acc[4] = {{0.f, 0.f}, {0.f, 0.f}, {0.f, 0.f}, {0.f, 0.f}};

    if (es == 0) acc_u4(acc, *(const uint4*)&g32[(size_t)node * 32 + fc * 4]);

    int j = s0 + es;
    for (; j + 24 < s1; j += 32) {
        int a0 = srcs[j];
        int a1 = srcs[j + 8];
        int a2 = srcs[j + 16];
        int a3 = srcs[j + 24];
        uint4 u0 = *(const uint4*)&g32[(size_t)a0 * 32 + fc * 4];
        uint4 u1 = *(const uint4*)&g32[(size_t)a1 * 32 + fc * 4];
        uint4 u2 = *(const uint4*)&g32[(size_t)a2 * 32 + fc * 4];
        uint4 u3 = *(const uint4*)&g32[(size_t)a3 * 32 + fc * 4];
        acc_u4(acc, u0);
        acc_u4(acc, u1);
        acc_u4(acc, u2);
        acc_u4(acc, u3);
    }
    for (; j + 8 < s1; j += 16) {
        int a0 = srcs[j];
        int a1 = srcs[j + 8];
        uint4 u0 = *(const uint4*)&g32[(size_t)a0 * 32 + fc * 4];
        uint4 u1 = *(const uint4*)&g32[(size_t)a1 * 32 + fc * 4];
        acc_u4(acc, u0);
        acc_u4(acc, u1);
    }
    if (j < s1) acc_u4(acc, *(const uint4*)&g32[(size_t)srcs[j] * 32 + fc * 4]);

#pragma unroll
    for (int q = 0; q < 4; q++) {
        acc[q].x += __shfl_xor(acc[q].x, 8, 64);
        acc[q].y += __shfl_xor(acc[q].y, 8, 64);
        acc[q].x += __shfl_xor(acc[q].x, 16, 64);
        acc[q].y += __shfl_xor(acc[q].y, 16, 64);
        acc[q].x += __shfl_xor(acc[q].x, 32, 64);
        acc[q].y += __shfl_xor(acc[q].y, 32, 64);
    }

    if (es == 0) {
        float di = dinv[node];
        float4 b0 = *(const float4*)&b[fc * 8];
        float4 b1 = *(const float4*)&b[fc * 8 + 4];
        float4 o0, o1;
        o0.x = fmaxf(di * acc[0].x + b0.x, 0.f);
        o0.y = fmaxf(di * acc[0].y + b0.y, 0.f);
        o0.z = fmaxf(di * acc[1].x + b0.z, 0.f);
        o0.w = fmaxf(di * acc[1].y + b0.w, 0.f);
        o1.x = fmaxf(di * acc[2].x + b1.x, 0.f);
        o1.y = fmaxf(di * acc[2].y + b1.y, 0.f);
        o1.z = fmaxf(di * acc[3].x + b1.z, 0.f);
        o1.w = fmaxf(di * acc[3].y + b1.w, 0.f);
        *(float4*)&out[(size_t)node * 64 + fc * 8]     = o0;
        *(float4*)&out[(size_t)node * 64 + fc * 8 + 4] = o1;
    }
}

// ---------------------------------------------------------------------------
// MLP head — unchanged
// ---------------------------------------------------------------------------
__global__ __launch_bounds__(128) void head_kernel(const float* __restrict__ h,
                                                   const float* __restrict__ Wh1,
                                                   const float* __restrict__ bh1,
                                                   const float* __restrict__ Wh2,
                                                   const float* __restrict__ bh2,
                                                   float* __restrict__ out, int n) {
    __shared__ float xs[128 * 65];
    __shared__ float w1s[64 * 32];
    __shared__ float w2s[64];
    __shared__ float b1s[32];
    __shared__ float b2s[2];
    const int t  = threadIdx.x;
    const int r0 = blockIdx.x * 128;

#pragma unroll
    for (int i = 0; i < 4; i++) {
        int off = (i * 128 + t) * 4;
        *(float4*)&w1s[off] = *(const float4*)&Wh1[off];
    }
    if (t < 64) w2s[t] = Wh2[t];
    if (t < 32) b1s[t] = bh1[t];
    if (t < 2)  b2s[t] = bh2[t];

#pragma unroll
    for (int i = 0; i < 16; i++) {
        int linear = i * 128 + t;
        int row = linear >> 4;
        int k4  = linear & 15;
        float4 v = {0.f, 0.f, 0.f, 0.f};
        int gr = r0 + row;
        if (gr < n) v = *(const float4*)&h[(size_t)gr * 64 + k4 * 4];
        int base = row * 65 + k4 * 4;
        xs[base + 0] = v.x;
        xs[base + 1] = v.y;
        xs[base + 2] = v.z;
        xs[base + 3] = v.w;
    }
    __syncthreads();

    float hid[32];
#pragma unroll
    for (int j = 0; j < 32; j++) hid[j] = b1s[j];

#pragma unroll 4
    for (int k = 0; k < 64; k++) {
        float xv = xs[t * 65 + k];
#pragma unroll
        for (int j4 = 0; j4 < 8; j4++) {
            float4 w = *(const float4*)&w1s[k * 32 + j4 * 4];
            hid[j4 * 4 + 0] += xv * w.x;
            hid[j4 * 4 + 1] += xv * w.y;
            hid[j4 * 4 + 2] += xv * w.z;
            hid[j4 * 4 + 3] += xv * w.w;
        }
    }

    float o0 = b2s[0], o1 = b2s[1];
#pragma unroll
    for (int j = 0; j < 32; j++) {
        float hv = fmaxf(hid[j], 0.f);
        o0 += hv * w2s[j * 2 + 0];
        o1 += hv * w2s[j * 2 + 1];
    }
    int gr = r0 + t;
    if (gr < n) {
        out[(size_t)gr * 2 + 0] = o0;
        out[(size_t)gr * 2 + 1] = o1;
    }
}

// ---------------------------------------------------------------------------
extern "C" void kernel_launch(void* const* d_in, const int* in_sizes, int n_in,
                              void* d_out, int out_size, void* d_ws, size_t ws_size,
                              hipStream_t stream) {
    const float* x   = (const float*)d_in[0];
    const void*  ei  = d_in[1];
    const float* W1  = (const float*)d_in[2];
    const float* b1  = (const float*)d_in[3];
    const float* W2  = (const float*)d_in[4];
    const float* b2  = (const float*)d_in[5];
    const float* Wh1 = (const float*)d_in[6];
    const float* bh1 = (const float*)d_in[7];
    const float* Wh2 = (const float*)d_in[8];
    const float* bh2 = (const float*)d_in[9];
    float* out = (float*)d_out;

    const int n = in_sizes[0] / INCH;   // 100000
    const int E = in_sizes[1] / 2;      // 3200000
    const int nbuck = (n + 255) >> BSH; // 391
    const int CAP = ((2 * (E / nbuck) + 1023) / 1024) * 1024;

    char* ws = (char*)d_ws;
    size_t off = 0;
    auto carve = [&](size_t bytes) {
        size_t p = off;
        off = (off + bytes + 255) & ~(size_t)255;
        return p;
    };
    size_t stg_bytes  = (size_t)nbuck * CAP * 4;
    size_t g32_bytes  = (size_t)n * 32 * 4;
    size_t bufA_bytes = stg_bytes > g32_bytes ? stg_bytes : g32_bytes;

    int*            flag      = (int*)(ws + carve(256));
    int*            bcur      = (int*)(ws + carve(MAXBUCK * 4));
    int*            bbase     = (int*)(ws + carve((MAXBUCK + 1) * 4));
    int*            row_start = (int*)(ws + carve((size_t)(n + 1) * 4));
    float*          dinv      = (float*)(ws + carve((size_t)n * 4));
    int*            srcs      = (int*)(ws + carve((size_t)E * 4));
    unsigned*       bufA      = (unsigned*)(ws + carve(bufA_bytes));   // staged / g32
    float*          bufB      = (float*)(ws + carve((size_t)n * HIDF * 4));
    unsigned short* whi1      = (unsigned short*)(ws + carve(8 * 4 * 64 * 8 * 2));
    unsigned short* wlo1      = (unsigned short*)(ws + carve(8 * 4 * 64 * 8 * 2));
    unsigned short* whi2      = (unsigned short*)(ws + carve(2 * 4 * 64 * 8 * 2));
    unsigned short* wlo2      = (unsigned short*)(ws + carve(2 * 4 * 64 * 8 * 2));
    (void)ws_size;

    unsigned* staged = bufA;

    // ---- prep: W splits + edge-dtype detect + bcur zero (one launch) ----
    prep_kernel<<<11, 256, 0, stream>>>(W1, whi1, wlo1, W2, whi2, wlo2,
                                        (const unsigned*)ei, flag, bcur);

    // ---- CSR build (count-free multisplit) ----
    bin_records<<<(E + CHUNK - 1) / CHUNK, 512, 0, stream>>>(ei, flag, bcur, staged, E, CAP);
    bucket_scan<<<1, MAXBUCK, 0, stream>>>(bcur, bbase, row_start, nbuck, E, n);
    bucket_finalize<<<nbuck, 256, 0, stream>>>(staged, bcur, bbase, row_start, dinv, srcs, n, CAP);

    const int mfma_grid   = (n + 63) / 64;
    const int gather_grid = (n + 3) / 4;

    // ---- layer 1 ----
    gemm_mfma<INCH><<<mfma_grid, 256, 0, stream>>>(x, whi1, wlo1, dinv, bufA, n);
    gather_bf16<<<gather_grid, 256, 0, stream>>>(bufA, srcs, row_start, dinv, b1, bufB, n);

    // ---- layer 2 ----
    gemm_mfma<HIDF><<<mfma_grid, 256, 0, stream>>>(bufB, whi2, wlo2, dinv, bufA, n);
    gather_bf16<<<gather_grid, 256, 0, stream>>>(bufA, srcs, row_start, dinv, b2, bufB, n);

    // ---- head ----
    head_kernel<<<(n + 127) / 128, 128, 0, stream>>>(bufB, Wh1, bh1, Wh2, bh2, out, n);
}

// Round 16
// 244.919 us; speedup vs baseline: 1.1373x; 1.0306x over previous
//
#include <hip/hip_runtime.h>

#define INCH 256
#define HIDF 64
#define BSH 8              // 256 nodes per bucket
#define MAXBUCK 512        // supports n up to 131072
#define CHUNK 4096         // edges per bin block (256 threads x 16)

typedef __attribute__((ext_vector_type(8))) short short8v;  // 8 bf16 (4 VGPRs)
typedef __attribute__((ext_vector_type(4))) float f32x4;
typedef __attribute__((ext_vector_type(2))) float f32x2;

__device__ __forceinline__ int edge_at(const void* ei, int is64, long long i) {
    if (is64) return (int)((const long long*)ei)[i];
    return ((const int*)ei)[i];
}

// round-to-nearest-even f32 -> bf16 (as u16 in low bits)
__device__ __forceinline__ unsigned bf16rne(float f) {
    unsigned u = __float_as_uint(f);
    return (u + 0x7fffu + ((u >> 16) & 1u)) >> 16;
}

// scale two packed bf16 by s, repack
__device__ __forceinline__ unsigned scale_pk(unsigned u, float s) {
    float lo = __uint_as_float(u << 16) * s;
    float hi = __uint_as_float(u & 0xffff0000u) * s;
    return bf16rne(lo) | (bf16rne(hi) << 16);
}

// ---------------------------------------------------------------------------
// prep: blocks 0-7 split W1, blocks 8-9 split W2 (bf16 hi/lo, MFMA B-frag
// layout), block 10 = edge-dtype sniffer + bcur zeroing. One launch.
// ---------------------------------------------------------------------------
__device__ __forceinline__ void wsplit_body(const float* __restrict__ W,
                                            unsigned short* __restrict__ whi,
                                            unsigned short* __restrict__ wlo,
                                            int K, int tid) {
    int total = (K / 32) * 4 * 64;
    if (tid >= total) return;
    int lane = tid & 63;
    int nf   = (tid >> 6) & 3;
    int ks   = tid >> 8;
    int col  = nf * 16 + (lane & 15);
    int k0   = ks * 32 + (lane >> 4) * 8;
#pragma unroll
    for (int i = 0; i < 8; i++) {
        float w = W[(size_t)(k0 + i) * 64 + col];
        unsigned u = __float_as_uint(w);
        float hif = __uint_as_float(u & 0xffff0000u);
        whi[(size_t)tid * 8 + i] = (unsigned short)(u >> 16);
        wlo[(size_t)tid * 8 + i] = (unsigned short)(__float_as_uint(w - hif) >> 16);
    }
}

__global__ __launch_bounds__(256) void prep_kernel(const float* __restrict__ W1,
                                                   unsigned short* __restrict__ whi1,
                                                   unsigned short* __restrict__ wlo1,
                                                   const float* __restrict__ W2,
                                                   unsigned short* __restrict__ whi2,
                                                   unsigned short* __restrict__ wlo2,
                                                   const unsigned* __restrict__ ei,
                                                   int* __restrict__ flag,
                                                   int* __restrict__ bcur) {
    const int blk = blockIdx.x;
    const int t   = threadIdx.x;
    if (blk < 8) {
        wsplit_body(W1, whi1, wlo1, INCH, blk * 256 + t);
    } else if (blk < 10) {
        wsplit_body(W2, whi2, wlo2, HIDF, (blk - 8) * 256 + t);
    } else {
        __shared__ int nonzero;
        if (t == 0) nonzero = 0;
        __syncthreads();
        if (ei[2 * (size_t)t + 1] != 0u) nonzero = 1;
        __syncthreads();
        if (t == 0) *flag = (nonzero == 0) ? 1 : 0;
        bcur[t] = 0;
        bcur[t + 256] = 0;
    }
}

// ---------------------------------------------------------------------------
// fused kernel: blocks [0, gblocks) run layer-1 MFMA GEMM (no dinv scaling);
// blocks [gblocks, ...) run count-free multisplit edge binning. The two are
// data-independent (gemm: x,W1 -> g32=bufA; bin: edge_index -> staged=bufB)
// and overlap across CUs within one launch.
// ---------------------------------------------------------------------------
__device__ __forceinline__ void gemm1_body(const float* __restrict__ X,
                                           const unsigned short* __restrict__ whi,
                                           const unsigned short* __restrict__ wlo,
                                           unsigned* __restrict__ Y, int n,
                                           int gbid, unsigned* tile) {
    const int t    = threadIdx.x;
    const int wid  = t >> 6;
    const int lane = t & 63;
    const int r0   = gbid * 64;

    const int mrow = lane & 15;
    const int kg   = (lane >> 4) * 8;
    const int row  = r0 + wid * 16 + mrow;
    const bool rv  = row < n;

    f32x4 acc0 = {0.f, 0.f, 0.f, 0.f};
    f32x4 acc1 = {0.f, 0.f, 0.f, 0.f};
    f32x4 acc2 = {0.f, 0.f, 0.f, 0.f};
    f32x4 acc3 = {0.f, 0.f, 0.f, 0.f};

    for (int ks = 0; ks < INCH / 32; ks++) {
        float4 a0 = {0.f, 0.f, 0.f, 0.f}, a1 = {0.f, 0.f, 0.f, 0.f};
        if (rv) {
            const float* xp = &X[(size_t)row * INCH + ks * 32 + kg];
            a0 = *(const float4*)xp;
            a1 = *(const float4*)(xp + 4);
        }
        float av[8] = {a0.x, a0.y, a0.z, a0.w, a1.x, a1.y, a1.z, a1.w};
        short8v ahi, alo;
#pragma unroll
        for (int i = 0; i < 8; i++) {
            unsigned u = __float_as_uint(av[i]);
            ahi[i] = (short)(u >> 16);
            float hif = __uint_as_float(u & 0xffff0000u);
            alo[i] = (short)(__float_as_uint(av[i] - hif) >> 16);
        }
        const size_t bbase = ((size_t)ks * 4 * 64 + lane) * 8;
        short8v bh0 = *(const short8v*)&whi[bbase + 0 * 512];
        short8v bh1 = *(const short8v*)&whi[bbase + 1 * 512];
        short8v bh2 = *(const short8v*)&whi[bbase + 2 * 512];
        short8v bh3 = *(const short8v*)&whi[bbase + 3 * 512];
        short8v bl0 = *(const short8v*)&wlo[bbase + 0 * 512];
        short8v bl1 = *(const short8v*)&wlo[bbase + 1 * 512];
        short8v bl2 = *(const short8v*)&wlo[bbase + 2 * 512];
        short8v bl3 = *(const short8v*)&wlo[bbase + 3 * 512];

        acc0 = __builtin_amdgcn_mfma_f32_16x16x32_bf16(ahi, bh0, acc0, 0, 0, 0);
        acc1 = __builtin_amdgcn_mfma_f32_16x16x32_bf16(ahi, bh1, acc1, 0, 0, 0);
        acc2 = __builtin_amdgcn_mfma_f32_16x16x32_bf16(ahi, bh2, acc2, 0, 0, 0);
        acc3 = __builtin_amdgcn_mfma_f32_16x16x32_bf16(ahi, bh3, acc3, 0, 0, 0);
        acc0 = __builtin_amdgcn_mfma_f32_16x16x32_bf16(alo, bh0, acc0, 0, 0, 0);
        acc1 = __builtin_amdgcn_mfma_f32_16x16x32_bf16(alo, bh1, acc1, 0, 0, 0);
        acc2 = __builtin_amdgcn_mfma_f32_16x16x32_bf16(alo, bh2, acc2, 0, 0, 0);
        acc3 = __builtin_amdgcn_mfma_f32_16x16x32_bf16(alo, bh3, acc3, 0, 0, 0);
        acc0 = __builtin_amdgcn_mfma_f32_16x16x32_bf16(ahi, bl0, acc0, 0, 0, 0);
        acc1 = __builtin_amdgcn_mfma_f32_16x16x32_bf16(ahi, bl1, acc1, 0, 0, 0);
        acc2 = __builtin_amdgcn_mfma_f32_16x16x32_bf16(ahi, bl2, acc2, 0, 0, 0);
        acc3 = __builtin_amdgcn_mfma_f32_16x16x32_bf16(ahi, bl3, acc3, 0, 0, 0);
    }

    const int c15 = lane & 15;
#pragma unroll
    for (int nf = 0; nf < 4; nf++) {
        f32x4 a = (nf == 0) ? acc0 : (nf == 1) ? acc1 : (nf == 2) ? acc2 : acc3;
#pragma unroll
        for (int r = 0; r < 4; r++) {
            int m = (lane >> 4) * 4 + r;
            float v = a[r];
            float pv = __shfl_xor(v, 1, 64);
            if (!(lane & 1)) {
                unsigned u = bf16rne(v) | (bf16rne(pv) << 16);
                tile[(wid * 16 + m) * 36 + nf * 8 + (c15 >> 1)] = u;
            }
        }
    }
    __syncthreads();

    {
        int lrow = t >> 2;
        int cb   = (t & 3) * 8;
        if (r0 + lrow < n) {
            uint4 w0 = *(const uint4*)&tile[lrow * 36 + cb];
            uint4 w1 = *(const uint4*)&tile[lrow * 36 + cb + 4];
            *(uint4*)&Y[(size_t)(r0 + lrow) * 32 + cb]     = w0;
            *(uint4*)&Y[(size_t)(r0 + lrow) * 32 + cb + 4] = w1;
        }
    }
}

__device__ __forceinline__ void bin_body(const void* __restrict__ ei,
                                         const int* __restrict__ flag,
                                         int* __restrict__ bcur,
                                         unsigned* __restrict__ staged,
                                         int E, int CAP, int bbid, int* cnt, int* cur) {
    const int t = threadIdx.x;
    const int is64 = *flag;
    const long long base = (long long)bbid * CHUNK;

    for (int b = t; b < MAXBUCK; b += 256) cnt[b] = 0;
    __syncthreads();

    int sr[16], dr[16];
#pragma unroll
    for (int i = 0; i < 16; i++) {
        long long e = base + (long long)i * 256 + t;
        if (e < E) {
            sr[i] = edge_at(ei, is64, e);
            dr[i] = edge_at(ei, is64, (long long)E + e);
            atomicAdd(&cnt[dr[i] >> BSH], 1);
        } else {
            dr[i] = -1;
        }
    }
    __syncthreads();

    for (int b = t; b < MAXBUCK; b += 256)
        if (cnt[b]) cur[b] = b * CAP + atomicAdd(&bcur[b], cnt[b]);
    __syncthreads();

#pragma unroll
    for (int i = 0; i < 16; i++) {
        if (dr[i] >= 0) {
            int gpos = atomicAdd(&cur[dr[i] >> BSH], 1);
            staged[gpos] = (unsigned)sr[i] | ((unsigned)(dr[i] & 255) << 24);
        }
    }
}

__global__ __launch_bounds__(256) void fused_gemm1_bin(const float* __restrict__ X,
                                                       const unsigned short* __restrict__ whi,
                                                       const unsigned short* __restrict__ wlo,
                                                       unsigned* __restrict__ Y, int n,
                                                       int gblocks,
                                                       const void* __restrict__ ei,
                                                       const int* __restrict__ flag,
                                                       int* __restrict__ bcur,
                                                       unsigned* __restrict__ staged,
                                                       int E, int CAP) {
    __shared__ unsigned smem[64 * 36];   // 9216B: gemm tile / bin cnt+cur
    if ((int)blockIdx.x < gblocks) {
        gemm1_body(X, whi, wlo, Y, n, blockIdx.x, smem);
    } else {
        int* cnt = (int*)smem;
        int* cur = cnt + MAXBUCK;
        bin_body(ei, flag, bcur, staged, E, CAP, blockIdx.x - gblocks, cnt, cur);
    }
}

// ---------------------------------------------------------------------------
// bucket_scan — unchanged
// ---------------------------------------------------------------------------
__global__ void bucket_scan(const int* __restrict__ bcur, int* __restrict__ bbase,
                            int* __restrict__ row_start, int nbuck, int E, int n) {
    __shared__ int s[MAXBUCK];
    int t = threadIdx.x;
    int v = (t < nbuck) ? bcur[t] : 0;
    s[t] = v;
    __syncthreads();
    for (int off = 1; off < MAXBUCK; off <<= 1) {
        int add = (t >= off) ? s[t - off] : 0;
        __syncthreads();
        s[t] += add;
        __syncthreads();
    }
    if (t < nbuck) bbase[t] = s[t] - v;
    if (t == 0) {
        bbase[nbuck] = E;
        row_start[n] = E;
    }
}

// ---------------------------------------------------------------------------
// bucket_finalize: per-node hist + scan -> row_start, dinv, scatter srcs,
// AND scale g32 rows by dinv (folds layer-1's dinv[s] into the messages).
// ---------------------------------------------------------------------------
__global__ __launch_bounds__(256) void bucket_finalize(const unsigned* __restrict__ staged,
                                                       const int* __restrict__ bcnts,
                                                       const int* __restrict__ bbase,
                                                       int* __restrict__ row_start,
                                                       float* __restrict__ dinv,
                                                       int* __restrict__ srcs,
                                                       unsigned* __restrict__ g32,
                                                       int n, int CAP) {
    __shared__ int cnt[256];
    __shared__ int sc[256];
    __shared__ int cur[256];
    __shared__ float sdinv[256];
    const int b  = blockIdx.x;
    const int t  = threadIdx.x;
    const int d0 = b << BSH;
    const int r0 = bbase[b];
    const int cb = bcnts[b];
    const size_t sb = (size_t)b * CAP;

    cnt[t] = 0;
    __syncthreads();
    for (int j = t; j < cb; j += 256) {
        unsigned rec = staged[sb + j];
        atomicAdd(&cnt[rec >> 24], 1);
    }
    __syncthreads();

    int v = cnt[t];
    sc[t] = v;
    __syncthreads();
    for (int off = 1; off < 256; off <<= 1) {
        int add = (t >= off) ? sc[t - off] : 0;
        __syncthreads();
        sc[t] += add;
        __syncthreads();
    }
    int ex = sc[t] - v;

    int node = d0 + t;
    float di = rsqrtf((float)v + 1.0f);
    if (node < n) {
        row_start[node] = r0 + ex;
        dinv[node] = di;
    }
    sdinv[t] = di;
    cur[t] = r0 + ex;
    __syncthreads();

    for (int j = t; j < cb; j += 256) {
        unsigned rec = staged[sb + j];
        int pos = atomicAdd(&cur[rec >> 24], 1);
        srcs[pos] = (int)(rec & 0xffffffu);
    }

    // scale g32 rows of this bucket by dinv (8 lanes x 16B per row)
    for (int r = t >> 3; r < 256; r += 32) {
        int nd = d0 + r;
        if (nd < n) {
            float s = sdinv[r];
            uint4* gp = (uint4*)&g32[(size_t)nd * 32];
            uint4 u = gp[t & 7];
            u.x = scale_pk(u.x, s);
            u.y = scale_pk(u.y, s);
            u.z = scale_pk(u.z, s);
            u.w = scale_pk(u.w, s);
            gp[t & 7] = u;
        }
    }
}

// ---------------------------------------------------------------------------
// layer-2 MFMA GEMM (with dinv epilogue) — unchanged from round 15
// ---------------------------------------------------------------------------
template <int K>
__global__ __launch_bounds__(256) void gemm_mfma(const float* __restrict__ X,
                                                 const unsigned short* __restrict__ whi,
                                                 const unsigned short* __restrict__ wlo,
                                                 const float* __restrict__ dinv,
                                                 unsigned* __restrict__ Y, int n) {
    __shared__ unsigned tile[64 * 36];
    __shared__ float dl[64];
    const int t    = threadIdx.x;
    const int wid  = t >> 6;
    const int lane = t & 63;
    const int r0   = blockIdx.x * 64;

    if (t < 64) dl[t] = (r0 + t < n) ? dinv[r0 + t] : 0.f;
    __syncthreads();

    const int mrow = lane & 15;
    const int kg   = (lane >> 4) * 8;
    const int row  = r0 + wid * 16 + mrow;
    const bool rv  = row < n;

    f32x4 acc0 = {0.f, 0.f, 0.f, 0.f};
    f32x4 acc1 = {0.f, 0.f, 0.f, 0.f};
    f32x4 acc2 = {0.f, 0.f, 0.f, 0.f};
    f32x4 acc3 = {0.f, 0.f, 0.f, 0.f};

    for (int ks = 0; ks < K / 32; ks++) {
        float4 a0 = {0.f, 0.f, 0.f, 0.f}, a1 = {0.f, 0.f, 0.f, 0.f};
        if (rv) {
            const float* xp = &X[(size_t)row * K + ks * 32 + kg];
            a0 = *(const float4*)xp;
            a1 = *(const float4*)(xp + 4);
        }
        float av[8] = {a0.x, a0.y, a0.z, a0.w, a1.x, a1.y, a1.z, a1.w};
        short8v ahi, alo;
#pragma unroll
        for (int i = 0; i < 8; i++) {
            unsigned u = __float_as_uint(av[i]);
            ahi[i] = (short)(u >> 16);
            float hif = __uint_as_float(u & 0xffff0000u);
            alo[i] = (short)(__float_as_uint(av[i] - hif) >> 16);
        }
        const size_t bbase = ((size_t)ks * 4 * 64 + lane) * 8;
        short8v bh0 = *(const short8v*)&whi[bbase + 0 * 512];
        short8v bh1 = *(const short8v*)&whi[bbase + 1 * 512];
        short8v bh2 = *(const short8v*)&whi[bbase + 2 * 512];
        short8v bh3 = *(const short8v*)&whi[bbase + 3 * 512];
        short8v bl0 = *(const short8v*)&wlo[bbase + 0 * 512];
        short8v bl1 = *(const short8v*)&wlo[bbase + 1 * 512];
        short8v bl2 = *(const short8v*)&wlo[bbase + 2 * 512];
        short8v bl3 = *(const short8v*)&wlo[bbase + 3 * 512];

        acc0 = __builtin_amdgcn_mfma_f32_16x16x32_bf16(ahi, bh0, acc0, 0, 0, 0);
        acc1 = __builtin_amdgcn_mfma_f32_16x16x32_bf16(ahi, bh1, acc1, 0, 0, 0);
        acc2 = __builtin_amdgcn_mfma_f32_16x16x32_bf16(ahi, bh2, acc2, 0, 0, 0);
        acc3 = __builtin_amdgcn_mfma_f32_16x16x32_bf16(ahi, bh3, acc3, 0, 0, 0);
        acc0 = __builtin_amdgcn_mfma_f32_16x16x32_bf16(alo, bh0, acc0, 0, 0, 0);
        acc1 = __builtin_amdgcn_mfma_f32_16x16x32_bf16(alo, bh1, acc1, 0, 0, 0);
        acc2 = __builtin_amdgcn_mfma_f32_16x16x32_bf16(alo, bh2, acc2, 0, 0, 0);
        acc3 = __builtin_amdgcn_mfma_f32_16x16x32_bf16(alo, bh3, acc3, 0, 0, 0);
        acc0 = __builtin_amdgcn_mfma_f32_16x16x32_bf16(ahi, bl0, acc0, 0, 0, 0);
        acc1 = __builtin_amdgcn_mfma_f32_16x16x32_bf16(ahi, bl1, acc1, 0, 0, 0);
        acc2 = __builtin_amdgcn_mfma_f32_16x16x32_bf16(ahi, bl2, acc2, 0, 0, 0);
        acc3 = __builtin_amdgcn_mfma_f32_16x16x32_bf16(ahi, bl3, acc3, 0, 0, 0);
    }

    const int c15 = lane & 15;
#pragma unroll
    for (int nf = 0; nf < 4; nf++) {
        f32x4 a = (nf == 0) ? acc0 : (nf == 1) ? acc1 : (nf == 2) ? acc2 : acc3;
#pragma unroll
        for (int r = 0; r < 4; r++) {
            int m = (lane >> 4) * 4 + r;
            float v = a[r] * dl[wid * 16 + m];
            float pv = __shfl_xor(v, 1, 64);
            if (!(lane & 1)) {
                unsigned u = bf16rne(v) | (bf16rne(pv) << 16);
                tile[(wid * 16 + m) * 36 + nf * 8 + (c15 >> 1)] = u;
            }
        }
    }
    __syncthreads();

    {
        int lrow = t >> 2;
        int cb   = (t & 3) * 8;
        if (r0 + lrow < n) {
            uint4 w0 = *(const uint4*)&tile[lrow * 36 + cb];
            uint4 w1 = *(const uint4*)&tile[lrow * 36 + cb + 4];
            *(uint4*)&Y[(size_t)(r0 + lrow) * 32 + cb]     = w0;
            *(uint4*)&Y[(size_t)(r0 + lrow) * 32 + cb + 4] = w1;
        }
    }
}

// ---------------------------------------------------------------------------
// gather — unchanged (confirmed at L3 random-access floor)
// ---------------------------------------------------------------------------
__device__ __forceinline__ void acc_pair(f32x2& a, unsigned w) {
    f32x2 v;
    v.x = __uint_as_float(w << 16);
    v.y = __uint_as_float(w & 0xffff0000u);
    a += v;
}

__device__ __forceinline__ void acc_u4(f32x2* acc, uint4 u) {
    acc_pair(acc[0], u.x);
    acc_pair(acc[1], u.y);
    acc_pair(acc[2], u.z);
    acc_pair(acc[3], u.w);
}

__global__ __launch_bounds__(256) void gather_bf16(const unsigned* __restrict__ g32,
                                                   const int* __restrict__ srcs,
                                                   const int* __restrict__ row_start,
                                                   const float* __restrict__ dinv,
                                                   const float* __restrict__ b,
                                                   float* __restrict__ out, int n) {
    const int lane = threadIdx.x & 63;
    const int es   = lane >> 3;
    const int fc   = lane & 7;
    const int node = blockIdx.x * 4 + (threadIdx.x >> 6);
    if (node >= n) return;

    const int s0 = row_start[node];
    const int s1 = row_start[node + 1];

    f32x2 acc[4] = {{0.f, 0.f}, {0.f, 0.f}, {0.f, 0.f}, {0.f, 0.f}};

    if (es == 0) acc_u4(acc, *(const uint4*)&g32[(size_t)node * 32 + fc * 4]);

    int j = s0 + es;
    for (; j + 24 < s1; j += 32) {
        int a0 = srcs[j];
        int a1 = srcs[j + 8];
        int a2 = srcs[j + 16];
        int a3 = srcs[j + 24];
        uint4 u0 = *(const uint4*)&g32[(size_t)a0 * 32 + fc * 4];
        uint4 u1 = *(const uint4*)&g32[(size_t)a1 * 32 + fc * 4];
        uint4 u2 = *(const uint4*)&g32[(size_t)a2 * 32 + fc * 4];
        uint4 u3 = *(const uint4*)&g32[(size_t)a3 * 32 + fc * 4];
        acc_u4(acc, u0);
        acc_u4(acc, u1);
        acc_u4(acc, u2);
        acc_u4(acc, u3);
    }
    for (; j + 8 < s1; j += 16) {
        int a0 = srcs[j];
        int a1 = srcs[j + 8];
        uint4 u0 = *(const uint4*)&g32[(size_t)a0 * 32 + fc * 4];
        uint4 u1 = *(const uint4*)&g32[(size_t)a1 * 32 + fc * 4];
        acc_u4(acc, u0);
        acc_u4(acc, u1);
    }
    if (j < s1) acc_u4(acc, *(const uint4*)&g32[(size_t)srcs[j] * 32 + fc * 4]);

#pragma unroll
    for (int q = 0; q < 4; q++) {
        acc[q].x += __shfl_xor(acc[q].x, 8, 64);
        acc[q].y += __shfl_xor(acc[q].y, 8, 64);
        acc[q].x += __shfl_xor(acc[q].x, 16, 64);
        acc[q].y += __shfl_xor(acc[q].y, 16, 64);
        acc[q].x += __shfl_xor(acc[q].x, 32, 64);
        acc[q].y += __shfl_xor(acc[q].y, 32, 64);
    }

    if (es == 0) {
        float di = dinv[node];
        float4 b0 = *(const float4*)&b[fc * 8];
        float4 b1 = *(const float4*)&b[fc * 8 + 4];
        float4 o0, o1;
        o0.x = fmaxf(di * acc[0].x + b0.x, 0.f);
        o0.y = fmaxf(di * acc[0].y + b0.y, 0.f);
        o0.z = fmaxf(di * acc[1].x + b0.z, 0.f);
        o0.w = fmaxf(di * acc[1].y + b0.w, 0.f);
        o1.x = fmaxf(di * acc[2].x + b1.x, 0.f);
        o1.y = fmaxf(di * acc[2].y + b1.y, 0.f);
        o1.z = fmaxf(di * acc[3].x + b1.z, 0.f);
        o1.w = fmaxf(di * acc[3].y + b1.w, 0.f);
        *(float4*)&out[(size_t)node * 64 + fc * 8]     = o0;
        *(float4*)&out[(size_t)node * 64 + fc * 8 + 4] = o1;
    }
}

// ---------------------------------------------------------------------------
// MLP head — unchanged
// ---------------------------------------------------------------------------
__global__ __launch_bounds__(128) void head_kernel(const float* __restrict__ h,
                                                   const float* __restrict__ Wh1,
                                                   const float* __restrict__ bh1,
                                                   const float* __restrict__ Wh2,
                                                   const float* __restrict__ bh2,
                                                   float* __restrict__ out, int n) {
    __shared__ float xs[128 * 65];
    __shared__ float w1s[64 * 32];
    __shared__ float w2s[64];
    __shared__ float b1s[32];
    __shared__ float b2s[2];
    const int t  = threadIdx.x;
    const int r0 = blockIdx.x * 128;

#pragma unroll
    for (int i = 0; i < 4; i++) {
        int off = (i * 128 + t) * 4;
        *(float4*)&w1s[off] = *(const float4*)&Wh1[off];
    }
    if (t < 64) w2s[t] = Wh2[t];
    if (t < 32) b1s[t] = bh1[t];
    if (t < 2)  b2s[t] = bh2[t];

#pragma unroll
    for (int i = 0; i < 16; i++) {
        int linear = i * 128 + t;
        int row = linear >> 4;
        int k4  = linear & 15;
        float4 v = {0.f, 0.f, 0.f, 0.f};
        int gr = r0 + row;
        if (gr < n) v = *(const float4*)&h[(size_t)gr * 64 + k4 * 4];
        int base = row * 65 + k4 * 4;
        xs[base + 0] = v.x;
        xs[base + 1] = v.y;
        xs[base + 2] = v.z;
        xs[base + 3] = v.w;
    }
    __syncthreads();

    float hid[32];
#pragma unroll
    for (int j = 0; j < 32; j++) hid[j] = b1s[j];

#pragma unroll 4
    for (int k = 0; k < 64; k++) {
        float xv = xs[t * 65 + k];
#pragma unroll
        for (int j4 = 0; j4 < 8; j4++) {
            float4 w = *(const float4*)&w1s[k * 32 + j4 * 4];
            hid[j4 * 4 + 0] += xv * w.x;
            hid[j4 * 4 + 1] += xv * w.y;
            hid[j4 * 4 + 2] += xv * w.z;
            hid[j4 * 4 + 3] += xv * w.w;
        }
    }

    float o0 = b2s[0], o1 = b2s[1];
#pragma unroll
    for (int j = 0; j < 32; j++) {
        float hv = fmaxf(hid[j], 0.f);
        o0 += hv * w2s[j * 2 + 0];
        o1 += hv * w2s[j * 2 + 1];
    }
    int gr = r0 + t;
    if (gr < n) {
        out[(size_t)gr * 2 + 0] = o0;
        out[(size_t)gr * 2 + 1] = o1;
    }
}

// ---------------------------------------------------------------------------
extern "C" void kernel_launch(void* const* d_in, const int* in_sizes, int n_in,
                              void* d_out, int out_size, void* d_ws, size_t ws_size,
                              hipStream_t stream) {
    const float* x   = (const float*)d_in[0];
    const void*  ei  = d_in[1];
    const float* W1  = (const float*)d_in[2];
    const float* b1  = (const float*)d_in[3];
    const float* W2  = (const float*)d_in[4];
    const float* b2  = (const float*)d_in[5];
    const float* Wh1 = (const float*)d_in[6];
    const float* bh1 = (const float*)d_in[7];
    const float* Wh2 = (const float*)d_in[8];
    const float* bh2 = (const float*)d_in[9];
    float* out = (float*)d_out;

    const int n = in_sizes[0] / INCH;   // 100000
    const int E = in_sizes[1] / 2;      // 3200000
    const int nbuck = (n + 255) >> BSH; // 391
    const int CAP = ((2 * (E / nbuck) + 1023) / 1024) * 1024;

    char* ws = (char*)d_ws;
    size_t off = 0;
    auto carve = [&](size_t bytes) {
        size_t p = off;
        off = (off + bytes + 255) & ~(size_t)255;
        return p;
    };
    size_t stg_bytes  = (size_t)nbuck * CAP * 4;
    size_t h_bytes    = (size_t)n * HIDF * 4;
    size_t bufB_bytes = stg_bytes > h_bytes ? stg_bytes : h_bytes;

    int*            flag      = (int*)(ws + carve(256));
    int*            bcur      = (int*)(ws + carve(MAXBUCK * 4));
    int*            bbase     = (int*)(ws + carve((MAXBUCK + 1) * 4));
    int*            row_start = (int*)(ws + carve((size_t)(n + 1) * 4));
    float*          dinv      = (float*)(ws + carve((size_t)n * 4));
    int*            srcs      = (int*)(ws + carve((size_t)E * 4));
    unsigned*       bufA      = (unsigned*)(ws + carve((size_t)n * 32 * 4));  // g32
    float*          bufB      = (float*)(ws + carve(bufB_bytes));            // staged / h
    unsigned short* whi1      = (unsigned short*)(ws + carve(8 * 4 * 64 * 8 * 2));
    unsigned short* wlo1      = (unsigned short*)(ws + carve(8 * 4 * 64 * 8 * 2));
    unsigned short* whi2      = (unsigned short*)(ws + carve(2 * 4 * 64 * 8 * 2));
    unsigned short* wlo2      = (unsigned short*)(ws + carve(2 * 4 * 64 * 8 * 2));
    (void)ws_size;

    // staged aliases bufB (h): staged is dead before gather1 writes h.
    unsigned* staged = (unsigned*)bufB;

    const int mfma_grid   = (n + 63) / 64;            // 1563
    const int bin_grid    = (E + CHUNK - 1) / CHUNK;  // 782
    const int gather_grid = (n + 3) / 4;

    // ---- prep: W splits + edge-dtype detect + bcur zero ----
    prep_kernel<<<11, 256, 0, stream>>>(W1, whi1, wlo1, W2, whi2, wlo2,
                                        (const unsigned*)ei, flag, bcur);

    // ---- fused: layer-1 GEMM (no dinv) || edge binning ----
    fused_gemm1_bin<<<mfma_grid + bin_grid, 256, 0, stream>>>(
        x, whi1, wlo1, bufA, n, mfma_grid, ei, flag, bcur, staged, E, CAP);

    // ---- CSR finalize (+ g32 *= dinv) ----
    bucket_scan<<<1, MAXBUCK, 0, stream>>>(bcur, bbase, row_start, nbuck, E, n);
    bucket_finalize<<<nbuck, 256, 0, stream>>>(staged, bcur, bbase, row_start,
                                               dinv, srcs, bufA, n, CAP);

    // ---- layer 1 gather ----
    gather_bf16<<<gather_grid, 256, 0, stream>>>(bufA, srcs, row_start, dinv, b1, bufB, n);

    // ---- layer 2 ----
    gemm_mfma<HIDF><<<mfma_grid, 256, 0, stream>>>(bufB, whi2, wlo2, dinv, bufA, n);
    gather_bf16<<<gather_grid, 256, 0, stream>>>(bufA, srcs, row_start, dinv, b2, bufB, n);

    // ---- head ----
    head_kernel<<<(n + 127) / 128, 128, 0, stream>>>(bufB, Wh1, bh1, Wh2, bh2, out, n);
}

// Round 17
// 239.661 us; speedup vs baseline: 1.1622x; 1.0219x over previous
//
#include <hip/hip_runtime.h>

#define INCH 256
#define HIDF 64
#define BSH 8              // 256 nodes per bucket
#define MAXBUCK 512        // supports n up to 131072
#define CHUNK 4096         // edges per bin block (256 threads x 16)

typedef __attribute__((ext_vector_type(8))) short short8v;  // 8 bf16 (4 VGPRs)
typedef __attribute__((ext_vector_type(4))) float f32x4;
typedef __attribute__((ext_vector_type(2))) float f32x2;

__device__ __forceinline__ int edge_at(const void* ei, int is64, long long i) {
    if (is64) return (int)((const long long*)ei)[i];
    return ((const int*)ei)[i];
}

// round-to-nearest-even f32 -> bf16 (as u16 in low bits)
__device__ __forceinline__ unsigned bf16rne(float f) {
    unsigned u = __float_as_uint(f);
    return (u + 0x7fffu + ((u >> 16) & 1u)) >> 16;
}

// scale two packed bf16 by s, repack
__device__ __forceinline__ unsigned scale_pk(unsigned u, float s) {
    float lo = __uint_as_float(u << 16) * s;
    float hi = __uint_as_float(u & 0xffff0000u) * s;
    return bf16rne(lo) | (bf16rne(hi) << 16);
}

// ---------------------------------------------------------------------------
// prep: blocks 0-7 split W1, blocks 8-9 split W2 (bf16 hi/lo, MFMA B-frag
// layout), block 10 = edge-dtype sniffer + bcur zeroing. One launch.
// ---------------------------------------------------------------------------
__device__ __forceinline__ void wsplit_body(const float* __restrict__ W,
                                            unsigned short* __restrict__ whi,
                                            unsigned short* __restrict__ wlo,
                                            int K, int tid) {
    int total = (K / 32) * 4 * 64;
    if (tid >= total) return;
    int lane = tid & 63;
    int nf   = (tid >> 6) & 3;
    int ks   = tid >> 8;
    int col  = nf * 16 + (lane & 15);
    int k0   = ks * 32 + (lane >> 4) * 8;
#pragma unroll
    for (int i = 0; i < 8; i++) {
        float w = W[(size_t)(k0 + i) * 64 + col];
        unsigned u = __float_as_uint(w);
        float hif = __uint_as_float(u & 0xffff0000u);
        whi[(size_t)tid * 8 + i] = (unsigned short)(u >> 16);
        wlo[(size_t)tid * 8 + i] = (unsigned short)(__float_as_uint(w - hif) >> 16);
    }
}

__global__ __launch_bounds__(256) void prep_kernel(const float* __restrict__ W1,
                                                   unsigned short* __restrict__ whi1,
                                                   unsigned short* __restrict__ wlo1,
                                                   const float* __restrict__ W2,
                                                   unsigned short* __restrict__ whi2,
                                                   unsigned short* __restrict__ wlo2,
                                                   const unsigned* __restrict__ ei,
                                                   int* __restrict__ flag,
                                                   int* __restrict__ bcur) {
    const int blk = blockIdx.x;
    const int t   = threadIdx.x;
    if (blk < 8) {
        wsplit_body(W1, whi1, wlo1, INCH, blk * 256 + t);
    } else if (blk < 10) {
        wsplit_body(W2, whi2, wlo2, HIDF, (blk - 8) * 256 + t);
    } else {
        __shared__ int nonzero;
        if (t == 0) nonzero = 0;
        __syncthreads();
        if (ei[2 * (size_t)t + 1] != 0u) nonzero = 1;
        __syncthreads();
        if (t == 0) *flag = (nonzero == 0) ? 1 : 0;
        bcur[t] = 0;
        bcur[t + 256] = 0;
    }
}

// ---------------------------------------------------------------------------
// fused kernel, INTERLEAVED role mapping: blockIdx%3<2 -> gemm (2/3 of blocks)
// blockIdx%3==2 -> bin (1/3). Both roles co-resident from t=0 so gemm's
// HBM/MFMA overlaps bin's atomic/L2 phases.
// ---------------------------------------------------------------------------
__device__ __forceinline__ void gemm1_body(const float* __restrict__ X,
                                           const unsigned short* __restrict__ whi,
                                           const unsigned short* __restrict__ wlo,
                                           unsigned* __restrict__ Y, int n,
                                           int gbid, unsigned* tile) {
    const int t    = threadIdx.x;
    const int wid  = t >> 6;
    const int lane = t & 63;
    const int r0   = gbid * 64;

    const int mrow = lane & 15;
    const int kg   = (lane >> 4) * 8;
    const int row  = r0 + wid * 16 + mrow;
    const bool rv  = row < n;

    f32x4 acc0 = {0.f, 0.f, 0.f, 0.f};
    f32x4 acc1 = {0.f, 0.f, 0.f, 0.f};
    f32x4 acc2 = {0.f, 0.f, 0.f, 0.f};
    f32x4 acc3 = {0.f, 0.f, 0.f, 0.f};

    for (int ks = 0; ks < INCH / 32; ks++) {
        float4 a0 = {0.f, 0.f, 0.f, 0.f}, a1 = {0.f, 0.f, 0.f, 0.f};
        if (rv) {
            const float* xp = &X[(size_t)row * INCH + ks * 32 + kg];
            a0 = *(const float4*)xp;
            a1 = *(const float4*)(xp + 4);
        }
        float av[8] = {a0.x, a0.y, a0.z, a0.w, a1.x, a1.y, a1.z, a1.w};
        short8v ahi, alo;
#pragma unroll
        for (int i = 0; i < 8; i++) {
            unsigned u = __float_as_uint(av[i]);
            ahi[i] = (short)(u >> 16);
            float hif = __uint_as_float(u & 0xffff0000u);
            alo[i] = (short)(__float_as_uint(av[i] - hif) >> 16);
        }
        const size_t bbase = ((size_t)ks * 4 * 64 + lane) * 8;
        short8v bh0 = *(const short8v*)&whi[bbase + 0 * 512];
        short8v bh1 = *(const short8v*)&whi[bbase + 1 * 512];
        short8v bh2 = *(const short8v*)&whi[bbase + 2 * 512];
        short8v bh3 = *(const short8v*)&whi[bbase + 3 * 512];
        short8v bl0 = *(const short8v*)&wlo[bbase + 0 * 512];
        short8v bl1 = *(const short8v*)&wlo[bbase + 1 * 512];
        short8v bl2 = *(const short8v*)&wlo[bbase + 2 * 512];
        short8v bl3 = *(const short8v*)&wlo[bbase + 3 * 512];

        acc0 = __builtin_amdgcn_mfma_f32_16x16x32_bf16(ahi, bh0, acc0, 0, 0, 0);
        acc1 = __builtin_amdgcn_mfma_f32_16x16x32_bf16(ahi, bh1, acc1, 0, 0, 0);
        acc2 = __builtin_amdgcn_mfma_f32_16x16x32_bf16(ahi, bh2, acc2, 0, 0, 0);
        acc3 = __builtin_amdgcn_mfma_f32_16x16x32_bf16(ahi, bh3, acc3, 0, 0, 0);
        acc0 = __builtin_amdgcn_mfma_f32_16x16x32_bf16(alo, bh0, acc0, 0, 0, 0);
        acc1 = __builtin_amdgcn_mfma_f32_16x16x32_bf16(alo, bh1, acc1, 0, 0, 0);
        acc2 = __builtin_amdgcn_mfma_f32_16x16x32_bf16(alo, bh2, acc2, 0, 0, 0);
        acc3 = __builtin_amdgcn_mfma_f32_16x16x32_bf16(alo, bh3, acc3, 0, 0, 0);
        acc0 = __builtin_amdgcn_mfma_f32_16x16x32_bf16(ahi, bl0, acc0, 0, 0, 0);
        acc1 = __builtin_amdgcn_mfma_f32_16x16x32_bf16(ahi, bl1, acc1, 0, 0, 0);
        acc2 = __builtin_amdgcn_mfma_f32_16x16x32_bf16(ahi, bl2, acc2, 0, 0, 0);
        acc3 = __builtin_amdgcn_mfma_f32_16x16x32_bf16(ahi, bl3, acc3, 0, 0, 0);
    }

    const int c15 = lane & 15;
#pragma unroll
    for (int nf = 0; nf < 4; nf++) {
        f32x4 a = (nf == 0) ? acc0 : (nf == 1) ? acc1 : (nf == 2) ? acc2 : acc3;
#pragma unroll
        for (int r = 0; r < 4; r++) {
            int m = (lane >> 4) * 4 + r;
            float v = a[r];
            float pv = __shfl_xor(v, 1, 64);
            if (!(lane & 1)) {
                unsigned u = bf16rne(v) | (bf16rne(pv) << 16);
                tile[(wid * 16 + m) * 36 + nf * 8 + (c15 >> 1)] = u;
            }
        }
    }
    __syncthreads();

    {
        int lrow = t >> 2;
        int cb   = (t & 3) * 8;
        if (r0 + lrow < n) {
            uint4 w0 = *(const uint4*)&tile[lrow * 36 + cb];
            uint4 w1 = *(const uint4*)&tile[lrow * 36 + cb + 4];
            *(uint4*)&Y[(size_t)(r0 + lrow) * 32 + cb]     = w0;
            *(uint4*)&Y[(size_t)(r0 + lrow) * 32 + cb + 4] = w1;
        }
    }
}

__device__ __forceinline__ void bin_body(const void* __restrict__ ei,
                                         const int* __restrict__ flag,
                                         int* __restrict__ bcur,
                                         unsigned* __restrict__ staged,
                                         int E, int CAP, int bbid, int* cnt, int* cur) {
    const int t = threadIdx.x;
    const int is64 = *flag;
    const long long base = (long long)bbid * CHUNK;

    for (int b = t; b < MAXBUCK; b += 256) cnt[b] = 0;
    __syncthreads();

    int sr[16], dr[16];
#pragma unroll
    for (int i = 0; i < 16; i++) {
        long long e = base + (long long)i * 256 + t;
        if (e < E) {
            sr[i] = edge_at(ei, is64, e);
            dr[i] = edge_at(ei, is64, (long long)E + e);
            atomicAdd(&cnt[dr[i] >> BSH], 1);
        } else {
            dr[i] = -1;
        }
    }
    __syncthreads();

    for (int b = t; b < MAXBUCK; b += 256)
        if (cnt[b]) cur[b] = b * CAP + atomicAdd(&bcur[b], cnt[b]);
    __syncthreads();

#pragma unroll
    for (int i = 0; i < 16; i++) {
        if (dr[i] >= 0) {
            int gpos = atomicAdd(&cur[dr[i] >> BSH], 1);
            staged[gpos] = (unsigned)sr[i] | ((unsigned)(dr[i] & 255) << 24);
        }
    }
}

__global__ __launch_bounds__(256) void fused_gemm1_bin(const float* __restrict__ X,
                                                       const unsigned short* __restrict__ whi,
                                                       const unsigned short* __restrict__ wlo,
                                                       unsigned* __restrict__ Y, int n,
                                                       int gblocks,
                                                       const void* __restrict__ ei,
                                                       const int* __restrict__ flag,
                                                       int* __restrict__ bcur,
                                                       unsigned* __restrict__ staged,
                                                       int E, int CAP, int bblocks) {
    __shared__ unsigned smem[64 * 36];   // 9216B: gemm tile / bin cnt+cur
    const int grp = blockIdx.x / 3;
    const int r   = blockIdx.x % 3;
    if (r < 2) {
        int gid = grp * 2 + r;
        if (gid < gblocks) gemm1_body(X, whi, wlo, Y, n, gid, smem);
    } else {
        int bid = grp;
        if (bid < bblocks) {
            int* cnt = (int*)smem;
            int* cur = cnt + MAXBUCK;
            bin_body(ei, flag, bcur, staged, E, CAP, bid, cnt, cur);
        }
    }
}

// ---------------------------------------------------------------------------
// bucket_scan — unchanged
// ---------------------------------------------------------------------------
__global__ void bucket_scan(const int* __restrict__ bcur, int* __restrict__ bbase,
                            int* __restrict__ row_start, int nbuck, int E, int n) {
    __shared__ int s[MAXBUCK];
    int t = threadIdx.x;
    int v = (t < nbuck) ? bcur[t] : 0;
    s[t] = v;
    __syncthreads();
    for (int off = 1; off < MAXBUCK; off <<= 1) {
        int add = (t >= off) ? s[t - off] : 0;
        __syncthreads();
        s[t] += add;
        __syncthreads();
    }
    if (t < nbuck) bbase[t] = s[t] - v;
    if (t == 0) {
        bbase[nbuck] = E;
        row_start[n] = E;
    }
}

// ---------------------------------------------------------------------------
// bucket_finalize: per-node hist + scan -> row_start, dinv, scatter srcs,
// AND scale g32 rows by dinv (folds layer-1's dinv[s] into the messages).
// ---------------------------------------------------------------------------
__global__ __launch_bounds__(256) void bucket_finalize(const unsigned* __restrict__ staged,
                                                       const int* __restrict__ bcnts,
                                                       const int* __restrict__ bbase,
                                                       int* __restrict__ row_start,
                                                       float* __restrict__ dinv,
                                                       int* __restrict__ srcs,
                                                       unsigned* __restrict__ g32,
                                                       int n, int CAP) {
    __shared__ int cnt[256];
    __shared__ int sc[256];
    __shared__ int cur[256];
    __shared__ float sdinv[256];
    const int b  = blockIdx.x;
    const int t  = threadIdx.x;
    const int d0 = b << BSH;
    const int r0 = bbase[b];
    const int cb = bcnts[b];
    const size_t sb = (size_t)b * CAP;

    cnt[t] = 0;
    __syncthreads();
    for (int j = t; j < cb; j += 256) {
        unsigned rec = staged[sb + j];
        atomicAdd(&cnt[rec >> 24], 1);
    }
    __syncthreads();

    int v = cnt[t];
    sc[t] = v;
    __syncthreads();
    for (int off = 1; off < 256; off <<= 1) {
        int add = (t >= off) ? sc[t - off] : 0;
        __syncthreads();
        sc[t] += add;
        __syncthreads();
    }
    int ex = sc[t] - v;

    int node = d0 + t;
    float di = rsqrtf((float)v + 1.0f);
    if (node < n) {
        row_start[node] = r0 + ex;
        dinv[node] = di;
    }
    sdinv[t] = di;
    cur[t] = r0 + ex;
    __syncthreads();

    for (int j = t; j < cb; j += 256) {
        unsigned rec = staged[sb + j];
        int pos = atomicAdd(&cur[rec >> 24], 1);
        srcs[pos] = (int)(rec & 0xffffffu);
    }

    // scale g32 rows of this bucket by dinv (8 lanes x 16B per row)
    for (int r = t >> 3; r < 256; r += 32) {
        int nd = d0 + r;
        if (nd < n) {
            float s = sdinv[r];
            uint4* gp = (uint4*)&g32[(size_t)nd * 32];
            uint4 u = gp[t & 7];
            u.x = scale_pk(u.x, s);
            u.y = scale_pk(u.y, s);
            u.z = scale_pk(u.z, s);
            u.w = scale_pk(u.w, s);
            gp[t & 7] = u;
        }
    }
}

// ---------------------------------------------------------------------------
// layer-2 MFMA GEMM (with dinv epilogue) — unchanged
// ---------------------------------------------------------------------------
template <int K>
__global__ __launch_bounds__(256) void gemm_mfma(const float* __restrict__ X,
                                                 const unsigned short* __restrict__ whi,
                                                 const unsigned short* __restrict__ wlo,
                                                 const float* __restrict__ dinv,
                                                 unsigned* __restrict__ Y, int n) {
    __shared__ unsigned tile[64 * 36];
    __shared__ float dl[64];
    const int t    = threadIdx.x;
    const int wid  = t >> 6;
    const int lane = t & 63;
    const int r0   = blockIdx.x * 64;

    if (t < 64) dl[t] = (r0 + t < n) ? dinv[r0 + t] : 0.f;
    __syncthreads();

    const int mrow = lane & 15;
    const int kg   = (lane >> 4) * 8;
    const int row  = r0 + wid * 16 + mrow;
    const bool rv  = row < n;

    f32x4 acc0 = {0.f, 0.f, 0.f, 0.f};
    f32x4 acc1 = {0.f, 0.f, 0.f, 0.f};
    f32x4 acc2 = {0.f, 0.f, 0.f, 0.f};
    f32x4 acc3 = {0.f, 0.f, 0.f, 0.f};

    for (int ks = 0; ks < K / 32; ks++) {
        float4 a0 = {0.f, 0.f, 0.f, 0.f}, a1 = {0.f, 0.f, 0.f, 0.f};
        if (rv) {
            const float* xp = &X[(size_t)row * K + ks * 32 + kg];
            a0 = *(const float4*)xp;
            a1 = *(const float4*)(xp + 4);
        }
        float av[8] = {a0.x, a0.y, a0.z, a0.w, a1.x, a1.y, a1.z, a1.w};
        short8v ahi, alo;
#pragma unroll
        for (int i = 0; i < 8; i++) {
            unsigned u = __float_as_uint(av[i]);
            ahi[i] = (short)(u >> 16);
            float hif = __uint_as_float(u & 0xffff0000u);
            alo[i] = (short)(__float_as_uint(av[i] - hif) >> 16);
        }
        const size_t bbase = ((size_t)ks * 4 * 64 + lane) * 8;
        short8v bh0 = *(const short8v*)&whi[bbase + 0 * 512];
        short8v bh1 = *(const short8v*)&whi[bbase + 1 * 512];
        short8v bh2 = *(const short8v*)&whi[bbase + 2 * 512];
        short8v bh3 = *(const short8v*)&whi[bbase + 3 * 512];
        short8v bl0 = *(const short8v*)&wlo[bbase + 0 * 512];
        short8v bl1 = *(const short8v*)&wlo[bbase + 1 * 512];
        short8v bl2 = *(const short8v*)&wlo[bbase + 2 * 512];
        short8v bl3 = *(const short8v*)&wlo[bbase + 3 * 512];

        acc0 = __builtin_amdgcn_mfma_f32_16x16x32_bf16(ahi, bh0, acc0, 0, 0, 0);
        acc1 = __builtin_amdgcn_mfma_f32_16x16x32_bf16(ahi, bh1, acc1, 0, 0, 0);
        acc2 = __builtin_amdgcn_mfma_f32_16x16x32_bf16(ahi, bh2, acc2, 0, 0, 0);
        acc3 = __builtin_amdgcn_mfma_f32_16x16x32_bf16(ahi, bh3, acc3, 0, 0, 0);
        acc0 = __builtin_amdgcn_mfma_f32_16x16x32_bf16(alo, bh0, acc0, 0, 0, 0);
        acc1 = __builtin_amdgcn_mfma_f32_16x16x32_bf16(alo, bh1, acc1, 0, 0, 0);
        acc2 = __builtin_amdgcn_mfma_f32_16x16x32_bf16(alo, bh2, acc2, 0, 0, 0);
        acc3 = __builtin_amdgcn_mfma_f32_16x16x32_bf16(alo, bh3, acc3, 0, 0, 0);
        acc0 = __builtin_amdgcn_mfma_f32_16x16x32_bf16(ahi, bl0, acc0, 0, 0, 0);
        acc1 = __builtin_amdgcn_mfma_f32_16x16x32_bf16(ahi, bl1, acc1, 0, 0, 0);
        acc2 = __builtin_amdgcn_mfma_f32_16x16x32_bf16(ahi, bl2, acc2, 0, 0, 0);
        acc3 = __builtin_amdgcn_mfma_f32_16x16x32_bf16(ahi, bl3, acc3, 0, 0, 0);
    }

    const int c15 = lane & 15;
#pragma unroll
    for (int nf = 0; nf < 4; nf++) {
        f32x4 a = (nf == 0) ? acc0 : (nf == 1) ? acc1 : (nf == 2) ? acc2 : acc3;
#pragma unroll
        for (int r = 0; r < 4; r++) {
            int m = (lane >> 4) * 4 + r;
            float v = a[r] * dl[wid * 16 + m];
            float pv = __shfl_xor(v, 1, 64);
            if (!(lane & 1)) {
                unsigned u = bf16rne(v) | (bf16rne(pv) << 16);
                tile[(wid * 16 + m) * 36 + nf * 8 + (c15 >> 1)] = u;
            }
        }
    }
    __syncthreads();

    {
        int lrow = t >> 2;
        int cb   = (t & 3) * 8;
        if (r0 + lrow < n) {
            uint4 w0 = *(const uint4*)&tile[lrow * 36 + cb];
            uint4 w1 = *(const uint4*)&tile[lrow * 36 + cb + 4];
            *(uint4*)&Y[(size_t)(r0 + lrow) * 32 + cb]     = w0;
            *(uint4*)&Y[(size_t)(r0 + lrow) * 32 + cb + 4] = w1;
        }
    }
}

// ---------------------------------------------------------------------------
// gather — unchanged (confirmed at L3 random-access floor)
// ---------------------------------------------------------------------------
__device__ __forceinline__ void acc_pair(f32x2& a, unsigned w) {
    f32x2 v;
    v.x = __uint_as_float(w << 16);
    v.y = __uint_as_float(w & 0xffff0000u);
    a += v;
}

__device__ __forceinline__ void acc_u4(f32x2* acc, uint4 u) {
    acc_pair(acc[0], u.x);
    acc_pair(acc[1], u.y);
    acc_pair(acc[2], u.z);
    acc_pair(acc[3], u.w);
}

__global__ __launch_bounds__(256) void gather_bf16(const unsigned* __restrict__ g32,
                                                   const int* __restrict__ srcs,
                                                   const int* __restrict__ row_start,
                                                   const float* __restrict__ dinv,
                                                   const float* __restrict__ b,
                                                   float* __restrict__ out, int n) {
    const int lane = threadIdx.x & 63;
    const int es   = lane >> 3;
    const int fc   = lane & 7;
    const int node = blockIdx.x * 4 + (threadIdx.x >> 6);
    if (node >= n) return;

    const int s0 = row_start[node];
    const int s1 = row_start[node + 1];

    f32x2 acc[4] = {{0.f, 0.f}, {0.f, 0.f}, {0.f, 0.f}, {0.f, 0.f}};

    if (es == 0) acc_u4(acc, *(const uint4*)&g32[(size_t)node * 32 + fc * 4]);

    int j = s0 + es;
    for (; j + 24 < s1; j += 32) {
        int a0 = srcs[j];
        int a1 = srcs[j + 8];
        int a2 = srcs[j + 16];
        int a3 = srcs[j + 24];
        uint4 u0 = *(const uint4*)&g32[(size_t)a0 * 32 + fc * 4];
        uint4 u1 = *(const uint4*)&g32[(size_t)a1 * 32 + fc * 4];
        uint4 u2 = *(const uint4*)&g32[(size_t)a2 * 32 + fc * 4];
        uint4 u3 = *(const uint4*)&g32[(size_t)a3 * 32 + fc * 4];
        acc_u4(acc, u0);
        acc_u4(acc, u1);
        acc_u4(acc, u2);
        acc_u4(acc, u3);
    }
    for (; j + 8 < s1; j += 16) {
        int a0 = srcs[j];
        int a1 = srcs[j + 8];
        uint4 u0 = *(const uint4*)&g32[(size_t)a0 * 32 + fc * 4];
        uint4 u1 = *(const uint4*)&g32[(size_t)a1 * 32 + fc * 4];
        acc_u4(acc, u0);
        acc_u4(acc, u1);
    }
    if (j < s1) acc_u4(acc, *(const uint4*)&g32[(size_t)srcs[j] * 32 + fc * 4]);

#pragma unroll
    for (int q = 0; q < 4; q++) {
        acc[q].x += __shfl_xor(acc[q].x, 8, 64);
        acc[q].y += __shfl_xor(acc[q].y, 8, 64);
        acc[q].x += __shfl_xor(acc[q].x, 16, 64);
        acc[q].y += __shfl_xor(acc[q].y, 16, 64);
        acc[q].x += __shfl_xor(acc[q].x, 32, 64);
        acc[q].y += __shfl_xor(acc[q].y, 32, 64);
    }

    if (es == 0) {
        float di = dinv[node];
        float4 b0 = *(const float4*)&b[fc * 8];
        float4 b1 = *(const float4*)&b[fc * 8 + 4];
        float4 o0, o1;
        o0.x = fmaxf(di * acc[0].x + b0.x, 0.f);
        o0.y = fmaxf(di * acc[0].y + b0.y, 0.f);
        o0.z = fmaxf(di * acc[1].x + b0.z, 0.f);
        o0.w = fmaxf(di * acc[1].y + b0.w, 0.f);
        o1.x = fmaxf(di * acc[2].x + b1.x, 0.f);
        o1.y = fmaxf(di * acc[2].y + b1.y, 0.f);
        o1.z = fmaxf(di * acc[3].x + b1.z, 0.f);
        o1.w = fmaxf(di * acc[3].y + b1.w, 0.f);
        *(float4*)&out[(size_t)node * 64 + fc * 8]     = o0;
        *(float4*)&out[(size_t)node * 64 + fc * 8 + 4] = o1;
    }
}

// ---------------------------------------------------------------------------
// MLP head — unchanged
// ---------------------------------------------------------------------------
__global__ __launch_bounds__(128) void head_kernel(const float* __restrict__ h,
                                                   const float* __restrict__ Wh1,
                                                   const float* __restrict__ bh1,
                                                   const float* __restrict__ Wh2,
                                                   const float* __restrict__ bh2,
                                                   float* __restrict__ out, int n) {
    __shared__ float xs[128 * 65];
    __shared__ float w1s[64 * 32];
    __shared__ float w2s[64];
    __shared__ float b1s[32];
    __shared__ float b2s[2];
    const int t  = threadIdx.x;
    const int r0 = blockIdx.x * 128;

#pragma unroll
    for (int i = 0; i < 4; i++) {
        int off = (i * 128 + t) * 4;
        *(float4*)&w1s[off] = *(const float4*)&Wh1[off];
    }
    if (t < 64) w2s[t] = Wh2[t];
    if (t < 32) b1s[t] = bh1[t];
    if (t < 2)  b2s[t] = bh2[t];

#pragma unroll
    for (int i = 0; i < 16; i++) {
        int linear = i * 128 + t;
        int row = linear >> 4;
        int k4  = linear & 15;
        float4 v = {0.f, 0.f, 0.f, 0.f};
        int gr = r0 + row;
        if (gr < n) v = *(const float4*)&h[(size_t)gr * 64 + k4 * 4];
        int base = row * 65 + k4 * 4;
        xs[base + 0] = v.x;
        xs[base + 1] = v.y;
        xs[base + 2] = v.z;
        xs[base + 3] = v.w;
    }
    __syncthreads();

    float hid[32];
#pragma unroll
    for (int j = 0; j < 32; j++) hid[j] = b1s[j];

#pragma unroll 4
    for (int k = 0; k < 64; k++) {
        float xv = xs[t * 65 + k];
#pragma unroll
        for (int j4 = 0; j4 < 8; j4++) {
            float4 w = *(const float4*)&w1s[k * 32 + j4 * 4];
            hid[j4 * 4 + 0] += xv * w.x;
            hid[j4 * 4 + 1] += xv * w.y;
            hid[j4 * 4 + 2] += xv * w.z;
            hid[j4 * 4 + 3] += xv * w.w;
        }
    }

    float o0 = b2s[0], o1 = b2s[1];
#pragma unroll
    for (int j = 0; j < 32; j++) {
        float hv = fmaxf(hid[j], 0.f);
        o0 += hv * w2s[j * 2 + 0];
        o1 += hv * w2s[j * 2 + 1];
    }
    int gr = r0 + t;
    if (gr < n) {
        out[(size_t)gr * 2 + 0] = o0;
        out[(size_t)gr * 2 + 1] = o1;
    }
}

// ---------------------------------------------------------------------------
extern "C" void kernel_launch(void* const* d_in, const int* in_sizes, int n_in,
                              void* d_out, int out_size, void* d_ws, size_t ws_size,
                              hipStream_t stream) {
    const float* x   = (const float*)d_in[0];
    const void*  ei  = d_in[1];
    const float* W1  = (const float*)d_in[2];
    const float* b1  = (const float*)d_in[3];
    const float* W2  = (const float*)d_in[4];
    const float* b2  = (const float*)d_in[5];
    const float* Wh1 = (const float*)d_in[6];
    const float* bh1 = (const float*)d_in[7];
    const float* Wh2 = (const float*)d_in[8];
    const float* bh2 = (const float*)d_in[9];
    float* out = (float*)d_out;

    const int n = in_sizes[0] / INCH;   // 100000
    const int E = in_sizes[1] / 2;      // 3200000
    const int nbuck = (n + 255) >> BSH; // 391
    const int CAP = ((2 * (E / nbuck) + 1023) / 1024) * 1024;

    char* ws = (char*)d_ws;
    size_t off = 0;
    auto carve = [&](size_t bytes) {
        size_t p = off;
        off = (off + bytes + 255) & ~(size_t)255;
        return p;
    };
    size_t stg_bytes  = (size_t)nbuck * CAP * 4;
    size_t h_bytes    = (size_t)n * HIDF * 4;
    size_t bufB_bytes = stg_bytes > h_bytes ? stg_bytes : h_bytes;

    int*            flag      = (int*)(ws + carve(256));
    int*            bcur      = (int*)(ws + carve(MAXBUCK * 4));
    int*            bbase     = (int*)(ws + carve((MAXBUCK + 1) * 4));
    int*            row_start = (int*)(ws + carve((size_t)(n + 1) * 4));
    float*          dinv      = (float*)(ws + carve((size_t)n * 4));
    int*            srcs      = (int*)(ws + carve((size_t)E * 4));
    unsigned*       bufA      = (unsigned*)(ws + carve((size_t)n * 32 * 4));  // g32
    float*          bufB      = (float*)(ws + carve(bufB_bytes));            // staged / h
    unsigned short* whi1      = (unsigned short*)(ws + carve(8 * 4 * 64 * 8 * 2));
    unsigned short* wlo1      = (unsigned short*)(ws + carve(8 * 4 * 64 * 8 * 2));
    unsigned short* whi2      = (unsigned short*)(ws + carve(2 * 4 * 64 * 8 * 2));
    unsigned short* wlo2      = (unsigned short*)(ws + carve(2 * 4 * 64 * 8 * 2));
    (void)ws_size;

    // staged aliases bufB (h): staged is dead before gather1 writes h.
    unsigned* staged = (unsigned*)bufB;

    const int mfma_grid   = (n + 63) / 64;            // 1563
    const int bin_grid    = (E + CHUNK - 1) / CHUNK;  // 782
    const int gather_grid = (n + 3) / 4;
    // interleaved fused grid: ceil(max(ceil(g/2), b)) groups of 3
    const int groups      = ((mfma_grid + 1) / 2) > bin_grid ? ((mfma_grid + 1) / 2) : bin_grid;
    const int fused_grid  = groups * 3;

    // ---- prep: W splits + edge-dtype detect + bcur zero ----
    prep_kernel<<<11, 256, 0, stream>>>(W1, whi1, wlo1, W2, whi2, wlo2,
                                        (const unsigned*)ei, flag, bcur);

    // ---- fused: layer-1 GEMM (no dinv) || edge binning, interleaved ----
    fused_gemm1_bin<<<fused_grid, 256, 0, stream>>>(
        x, whi1, wlo1, bufA, n, mfma_grid, ei, flag, bcur, staged, E, CAP, bin_grid);

    // ---- CSR finalize (+ g32 *= dinv) ----
    bucket_scan<<<1, MAXBUCK, 0, stream>>>(bcur, bbase, row_start, nbuck, E, n);
    bucket_finalize<<<nbuck, 256, 0, stream>>>(staged, bcur, bbase, row_start,
                                               dinv, srcs, bufA, n, CAP);

    // ---- layer 1 gather ----
    gather_bf16<<<gather_grid, 256, 0, stream>>>(bufA, srcs, row_start, dinv, b1, bufB, n);

    // ---- layer 2 ----
    gemm_mfma<HIDF><<<mfma_grid, 256, 0, stream>>>(bufB, whi2, wlo2, dinv, bufA, n);
    gather_bf16<<<gather_grid, 256, 0, stream>>>(bufA, srcs, row_start, dinv, b2, bufB, n);

    // ---- head ----
    head_kernel<<<(n + 127) / 128, 128, 0, stream>>>(bufB, Wh1, bh1, Wh2, bh2, out, n);
}